// Round 1
// baseline (17420.673 us; speedup 1.0000x reference)
//
#include <hip/hip_runtime.h>
#include <math.h>

#define H 512
#define Bb 128
#define Ii 32
#define Ll 96
#define Ss 16
#define Ff 24
#define STEPS 23
#define R 8

__device__ __forceinline__ float sigmoidf_(float x) { return 1.0f / (1.0f + expf(-x)); }
__device__ __forceinline__ float softplusf_(float x) {
    return fmaxf(x, 0.0f) + log1pf(expf(-fabsf(x)));
}
__device__ __forceinline__ float dot4(float4 a, float4 b) {
    return a.x * b.x + a.y * b.y + a.z * b.z + a.w * b.w;
}

// ---------------- Encoder GRU: one block per batch row ----------------
__global__ __launch_bounds__(512) void enc_kernel(
    const float* __restrict__ x, const float* __restrict__ Wih,
    const float* __restrict__ Whh, const float* __restrict__ bih,
    const float* __restrict__ bhh, float* __restrict__ h_out)
{
    __shared__ float sh[H];
    __shared__ float sx[Ii];
    const int b = blockIdx.x;
    const int t = threadIdx.x;

    sh[t] = 0.0f;

    const float bir = bih[t], biz = bih[H + t], bin = bih[2 * H + t];
    const float bhr = bhh[t], bhz = bhh[H + t], bhn = bhh[2 * H + t];
    const float4* wr4 = (const float4*)(Whh + (size_t)t * H);
    const float4* wz4 = (const float4*)(Whh + (size_t)(H + t) * H);
    const float4* wn4 = (const float4*)(Whh + (size_t)(2 * H + t) * H);
    const float* wir = Wih + (size_t)t * Ii;
    const float* wiz = Wih + (size_t)(H + t) * Ii;
    const float* win = Wih + (size_t)(2 * H + t) * Ii;

    for (int l = 0; l < Ll; ++l) {
        if (t < Ii) sx[t] = x[((size_t)b * Ii + t) * Ll + l];
        __syncthreads();  // sx ready; also orders prev-step h write vs reads

        // input-gate contributions (x row is only 32 wide)
        float gir = bir, giz = biz, gin = bin;
        #pragma unroll 8
        for (int i = 0; i < Ii; ++i) {
            float xv = sx[i];
            gir += xv * wir[i];
            giz += xv * wiz[i];
            gin += xv * win[i];
        }
        // hidden-gate dots over h (LDS broadcast reads)
        float ar = 0.0f, az = 0.0f, an = 0.0f;
        const float4* h4 = (const float4*)sh;
        #pragma unroll 4
        for (int j = 0; j < H / 4; ++j) {
            float4 hv = h4[j];
            ar += dot4(hv, wr4[j]);
            az += dot4(hv, wz4[j]);
            an += dot4(hv, wn4[j]);
        }
        float hold = sh[t];
        __syncthreads();  // all dot reads of h complete before update

        float r = sigmoidf_(gir + bhr + ar);
        float z = sigmoidf_(giz + bhz + az);
        float n = tanhf(gin + r * (an + bhn));
        sh[t] = (1.0f - z) * n + z * hold;
    }
    __syncthreads();
    h_out[(size_t)b * H + t] = sh[t];
}

// ------- SDE integration + decoder GRU + output projection, fused -------
// One block owns R=8 rows of the S*B=2048 merged batch for all steps.
__global__ __launch_bounds__(512) void sde_dec_kernel(
    const float* __restrict__ h_enc, const float* __restrict__ noise,
    const float* __restrict__ fW1, const float* __restrict__ fb1,
    const float* __restrict__ fW2, const float* __restrict__ fb2,
    const float* __restrict__ gW, const float* __restrict__ gb,
    const float* __restrict__ dWhh, const float* __restrict__ dbih,
    const float* __restrict__ dbhh,
    const float* __restrict__ outW, const float* __restrict__ outb,
    float* __restrict__ out)
{
    __shared__ float sh[R][H];   // h rows
    __shared__ float su[R][H];   // tanh(h W1^T + b1) intermediate
    const int t = threadIdx.x;
    const int row0 = blockIdx.x * R;

    // init h rows from encoder state (broadcast across samples)
    #pragma unroll
    for (int r = 0; r < R; ++r) {
        int row = row0 + r;
        int b = row & (Bb - 1);
        sh[r][t] = h_enc[(size_t)b * H + t];
    }
    __syncthreads();

    const float dt = (float)Ff / (float)STEPS;
    const float sqdt = sqrtf(dt);

    // ---- SDE: h <- h + f(h)*dt + g(h)*dW ----
    {
        const float4* w1 = (const float4*)(fW1 + (size_t)t * H);
        const float4* w2 = (const float4*)(fW2 + (size_t)t * H);
        const float4* wg = (const float4*)(gW + (size_t)t * H);
        const float b1 = fb1[t], b2 = fb2[t], bg = gb[t];

        for (int st = 0; st < STEPS; ++st) {
            // phase A: u = tanh(h @ W1^T + b1)
            float acc[R];
            #pragma unroll
            for (int r = 0; r < R; ++r) acc[r] = b1;
            for (int j = 0; j < H / 4; ++j) {
                float4 w = w1[j];
                #pragma unroll
                for (int r = 0; r < R; ++r) {
                    float4 hv = ((const float4*)sh[r])[j];
                    acc[r] += dot4(hv, w);
                }
            }
            #pragma unroll
            for (int r = 0; r < R; ++r) su[r][t] = tanhf(acc[r]);
            __syncthreads();

            // phase B: f = u @ W2^T + b2 ; g = softplus(h @ gW^T + gb)
            float fv[R], gv[R];
            #pragma unroll
            for (int r = 0; r < R; ++r) { fv[r] = b2; gv[r] = bg; }
            for (int j = 0; j < H / 4; ++j) {
                float4 wa = w2[j];
                float4 wb = wg[j];
                #pragma unroll
                for (int r = 0; r < R; ++r) {
                    float4 uv = ((const float4*)su[r])[j];
                    float4 hv = ((const float4*)sh[r])[j];
                    fv[r] += dot4(uv, wa);
                    gv[r] += dot4(hv, wb);
                }
            }
            __syncthreads();  // all reads of h done before update

            #pragma unroll
            for (int r = 0; r < R; ++r) {
                int row = row0 + r;
                int s = row >> 7;          // /Bb
                int b = row & (Bb - 1);
                float dw = noise[(((size_t)s * STEPS + st) * Bb + b) * H + t] * sqdt;
                sh[r][t] += fv[r] * dt + softplusf_(gv[r]) * dw;
            }
            __syncthreads();
        }
    }

    // ---- decoder GRU (zero input -> gi = dec_bih) + out projection ----
    {
        const float4* dwr = (const float4*)(dWhh + (size_t)t * H);
        const float4* dwz = (const float4*)(dWhh + (size_t)(H + t) * H);
        const float4* dwn = (const float4*)(dWhh + (size_t)(2 * H + t) * H);
        const float gir = dbih[t], giz = dbih[H + t], gin = dbih[2 * H + t];
        const float bhr = dbhh[t], bhz = dbhh[H + t], bhn = dbhh[2 * H + t];

        for (int st = 0; st < Ff; ++st) {
            float ar[R], az[R], an[R];
            #pragma unroll
            for (int r = 0; r < R; ++r) { ar[r] = 0.0f; az[r] = 0.0f; an[r] = 0.0f; }
            for (int j = 0; j < H / 4; ++j) {
                float4 wr = dwr[j];
                float4 wz = dwz[j];
                float4 wn = dwn[j];
                #pragma unroll
                for (int r = 0; r < R; ++r) {
                    float4 hv = ((const float4*)sh[r])[j];
                    ar[r] += dot4(hv, wr);
                    az[r] += dot4(hv, wz);
                    an[r] += dot4(hv, wn);
                }
            }
            __syncthreads();  // dots done before h update

            #pragma unroll
            for (int r = 0; r < R; ++r) {
                float rg = sigmoidf_(gir + bhr + ar[r]);
                float zg = sigmoidf_(giz + bhz + az[r]);
                float ng = tanhf(gin + rg * (bhn + an[r]));
                sh[r][t] = (1.0f - zg) * ng + zg * sh[r][t];
            }
            __syncthreads();  // h updated before out-proj reads

            // out projection: 256 active threads -> (row r, feature i)
            if (t < R * Ii) {
                int r = t >> 5;
                int i = t & (Ii - 1);
                const float4* wo = (const float4*)(outW + (size_t)i * H);
                float a = outb[i];
                for (int j = 0; j < H / 4; ++j) {
                    float4 hv = ((const float4*)sh[r])[j];
                    a += dot4(hv, wo[j]);
                }
                int row = row0 + r;
                int s = row >> 7;
                int b = row & (Bb - 1);
                out[(((size_t)s * Bb + b) * Ii + i) * Ff + st] = a;
            }
            __syncthreads();
        }
    }
}

extern "C" void kernel_launch(void* const* d_in, const int* in_sizes, int n_in,
                              void* d_out, int out_size, void* d_ws, size_t ws_size,
                              hipStream_t stream) {
    const float* x       = (const float*)d_in[0];
    const float* noise   = (const float*)d_in[1];
    const float* enc_Wih = (const float*)d_in[2];
    const float* enc_Whh = (const float*)d_in[3];
    const float* enc_bih = (const float*)d_in[4];
    const float* enc_bhh = (const float*)d_in[5];
    const float* f_W1    = (const float*)d_in[6];
    const float* f_b1    = (const float*)d_in[7];
    const float* f_W2    = (const float*)d_in[8];
    const float* f_b2    = (const float*)d_in[9];
    const float* g_W     = (const float*)d_in[10];
    const float* g_b     = (const float*)d_in[11];
    // d_in[12] = dec_Wih (unused: decoder input is zero)
    const float* dec_Whh = (const float*)d_in[13];
    const float* dec_bih = (const float*)d_in[14];
    const float* dec_bhh = (const float*)d_in[15];
    const float* out_W   = (const float*)d_in[16];
    const float* out_b   = (const float*)d_in[17];

    float* out   = (float*)d_out;
    float* h_enc = (float*)d_ws;  // 128*512 floats = 256 KB

    enc_kernel<<<Bb, 512, 0, stream>>>(x, enc_Wih, enc_Whh, enc_bih, enc_bhh, h_enc);
    sde_dec_kernel<<<(Ss * Bb) / R, 512, 0, stream>>>(
        h_enc, noise, f_W1, f_b1, f_W2, f_b2, g_W, g_b,
        dec_Whh, dec_bih, dec_bhh, out_W, out_b, out);
}

// Round 3
// 4894.728 us; speedup vs baseline: 3.5591x; 3.5591x over previous
//
#include <hip/hip_runtime.h>
#include <math.h>

typedef __bf16 bf16x8 __attribute__((ext_vector_type(8)));
typedef float f32x4 __attribute__((ext_vector_type(4)));

#define HD 512
#define NB 128
#define NI 32
#define NL 96
#define NS 16
#define NF 24
#define NSTEP 23
#define HBS 520   // padded bf16 LDS row stride

#define MFMA16(a, b, c) __builtin_amdgcn_mfma_f32_16x16x32_bf16(a, b, c, 0, 0, 0)

__device__ __forceinline__ unsigned short f2bf(float f) {
    union { float f; unsigned u; } v; v.f = f;
    unsigned r = v.u + 0x7fffu + ((v.u >> 16) & 1u);
    return (unsigned short)(r >> 16);
}
__device__ __forceinline__ float bf2f(unsigned short h) {
    union { unsigned u; float f; } v; v.u = ((unsigned)h) << 16;
    return v.f;
}
// exact two-term split: v = hi + lo + O(2^-18 * v)
__device__ __forceinline__ void split_bf(float v, unsigned short& hi, unsigned short& lo) {
    unsigned short h = f2bf(v);
    hi = h;
    lo = f2bf(v - bf2f(h));
}
__device__ __forceinline__ float sigm(float x) { return 1.0f / (1.0f + __expf(-x)); }
__device__ __forceinline__ float softp(float x) {
    return fmaxf(x, 0.0f) + log1pf(__expf(-fabsf(x)));
}
__device__ __forceinline__ bf16x8 ld8(const unsigned short* p) {
    return *reinterpret_cast<const bf16x8*>(p);
}
// 3-term split MFMA: C += (Ahi+Alo)(Bhi+Blo), dropping lo*lo
__device__ __forceinline__ f32x4 mfma3(bf16x8 ahi, bf16x8 alo, const unsigned short* bp, f32x4 c) {
    bf16x8 bhi = ld8(bp);
    bf16x8 blo = ld8(bp + 8);
    c = MFMA16(ahi, bhi, c);
    c = MFMA16(alo, bhi, c);
    c = MFMA16(ahi, blo, c);
    return c;
}

// ---------- prep: pack W[N][K] fp32 -> split bf16 fragments (hi 8, lo 8 per lane) ----------
// frag idx = (nt*(K/32)+kt)*64 + lane; covers W[nt*16+(lane&15)][kt*32+(lane>>4)*8 + j]
__global__ void pack_w(const float* __restrict__ W, unsigned short* __restrict__ Wp,
                       int N, int K) {
    int idx = blockIdx.x * 256 + threadIdx.x;
    int total = (N / 16) * (K / 32) * 64;
    if (idx >= total) return;
    int lane = idx & 63;
    int t2 = idx >> 6;
    int KT = K / 32;
    int kt = t2 % KT, nt = t2 / KT;
    const float* src = W + (size_t)(nt * 16 + (lane & 15)) * K + kt * 32 + (lane >> 4) * 8;
    unsigned short* dst = Wp + (size_t)idx * 16;
    #pragma unroll
    for (int j = 0; j < 8; ++j) split_bf(src[j], dst[j], dst[8 + j]);
}

// ---------- prep: x[B][I][L] fp32 -> xt_hi/xt_lo [L][B][I] bf16 ----------
__global__ void pack_x(const float* __restrict__ x, unsigned short* __restrict__ xhi,
                       unsigned short* __restrict__ xlo) {
    int idx = blockIdx.x * 256 + threadIdx.x;  // (l, b)
    if (idx >= NL * NB) return;
    int b = idx % NB, l = idx / NB;
    size_t base = (size_t)(l * NB + b) * NI;
    #pragma unroll
    for (int i = 0; i < NI; ++i)
        split_bf(x[((size_t)b * NI + i) * NL + l], xhi[base + i], xlo[base + i]);
}

// ---------------- Encoder GRU: 8 blocks x 16 rows, split MFMA ----------------
__global__ __launch_bounds__(512) void enc_mfma(
    const unsigned short* __restrict__ xhi, const unsigned short* __restrict__ xlo,
    const unsigned short* __restrict__ wih_p, const unsigned short* __restrict__ whh_p,
    const float* __restrict__ bih, const float* __restrict__ bhh,
    float* __restrict__ h_enc)
{
    __shared__ __align__(16) unsigned short hhi[16 * HBS];
    __shared__ __align__(16) unsigned short hlo[16 * HBS];
    const int tid = threadIdx.x, lane = tid & 63, wv = tid >> 6;
    const int l15 = lane & 15, g4 = lane >> 4;
    const int row0 = blockIdx.x * 16;
    const int col0 = wv * 64, c16 = col0 >> 4;

    float h[4][4];
    #pragma unroll
    for (int nt = 0; nt < 4; ++nt)
        #pragma unroll
        for (int v = 0; v < 4; ++v) h[nt][v] = 0.0f;
    for (int i = tid; i < 16 * HBS; i += 512) { hhi[i] = 0; hlo[i] = 0; }

    float cr[4], cz[4], binv[4], bhnv[4];
    #pragma unroll
    for (int nt = 0; nt < 4; ++nt) {
        int t = col0 + nt * 16 + l15;
        cr[nt] = bih[t] + bhh[t];
        cz[nt] = bih[HD + t] + bhh[HD + t];
        binv[nt] = bih[2 * HD + t];
        bhnv[nt] = bhh[2 * HD + t];
    }
    __syncthreads();

    const f32x4 zz = {0.f, 0.f, 0.f, 0.f};
    for (int l = 0; l < NL; ++l) {
        size_t xb = (size_t)(l * NB + row0 + l15) * NI + g4 * 8;
        bf16x8 axh = ld8(xhi + xb);
        bf16x8 axl = ld8(xlo + xb);
        f32x4 ar[4], az[4], anh[4], anx[4];
        #pragma unroll
        for (int nt = 0; nt < 4; ++nt) {
            // K=32 x-projection (1 k-tile per gate)
            ar[nt]  = mfma3(axh, axl, wih_p + ((size_t)(0 * 32 + c16 + nt) * 64 + lane) * 16, zz);
            az[nt]  = mfma3(axh, axl, wih_p + ((size_t)(1 * 32 + c16 + nt) * 64 + lane) * 16, zz);
            anx[nt] = mfma3(axh, axl, wih_p + ((size_t)(2 * 32 + c16 + nt) * 64 + lane) * 16, zz);
            anh[nt] = zz;
        }
        #pragma unroll 2
        for (int kt = 0; kt < 16; ++kt) {
            bf16x8 ah = ld8(&hhi[l15 * HBS + kt * 32 + g4 * 8]);
            bf16x8 al = ld8(&hlo[l15 * HBS + kt * 32 + g4 * 8]);
            #pragma unroll
            for (int nt = 0; nt < 4; ++nt) {
                ar[nt]  = mfma3(ah, al, whh_p + ((size_t)((0 * 32 + c16 + nt) * 16 + kt) * 64 + lane) * 16, ar[nt]);
                az[nt]  = mfma3(ah, al, whh_p + ((size_t)((1 * 32 + c16 + nt) * 16 + kt) * 64 + lane) * 16, az[nt]);
                anh[nt] = mfma3(ah, al, whh_p + ((size_t)((2 * 32 + c16 + nt) * 16 + kt) * 64 + lane) * 16, anh[nt]);
            }
        }
        __syncthreads();  // all h reads done before updates
        #pragma unroll
        for (int nt = 0; nt < 4; ++nt)
            #pragma unroll
            for (int v = 0; v < 4; ++v) {
                float r = sigm(ar[nt][v] + cr[nt]);
                float z = sigm(az[nt][v] + cz[nt]);
                float n = tanhf(anx[nt][v] + binv[nt] + r * (anh[nt][v] + bhnv[nt]));
                h[nt][v] = (1.0f - z) * n + z * h[nt][v];
                int off = (g4 * 4 + v) * HBS + col0 + nt * 16 + l15;
                split_bf(h[nt][v], hhi[off], hlo[off]);
            }
        __syncthreads();  // writes visible before next step's reads
    }
    #pragma unroll
    for (int nt = 0; nt < 4; ++nt)
        #pragma unroll
        for (int v = 0; v < 4; ++v)
            h_enc[(size_t)(row0 + g4 * 4 + v) * HD + col0 + nt * 16 + l15] = h[nt][v];
}

// -------- SDE + decoder GRU + out-proj: 128 blocks x 16 rows, split MFMA --------
__global__ __launch_bounds__(512) void sde_dec_mfma(
    const float* __restrict__ h_enc, const float* __restrict__ noise,
    const unsigned short* __restrict__ w1_p, const unsigned short* __restrict__ w2_p,
    const unsigned short* __restrict__ gw_p, const unsigned short* __restrict__ dwhh_p,
    const unsigned short* __restrict__ outw_p,
    const float* __restrict__ fb1, const float* __restrict__ fb2,
    const float* __restrict__ gb, const float* __restrict__ dbih,
    const float* __restrict__ dbhh, const float* __restrict__ outb,
    float* __restrict__ out)
{
    __shared__ __align__(16) unsigned short hhi[16 * HBS];
    __shared__ __align__(16) unsigned short hlo[16 * HBS];
    __shared__ __align__(16) unsigned short uhi[16 * HBS];
    __shared__ __align__(16) unsigned short ulo[16 * HBS];
    __shared__ float obuf[16][NI][NF];
    const int tid = threadIdx.x, lane = tid & 63, wv = tid >> 6;
    const int l15 = lane & 15, g4 = lane >> 4;
    const int row0 = blockIdx.x * 16;
    const int col0 = wv * 64, c16 = col0 >> 4;

    float h[4][4];
    #pragma unroll
    for (int nt = 0; nt < 4; ++nt)
        #pragma unroll
        for (int v = 0; v < 4; ++v) {
            int m = g4 * 4 + v;
            int t = col0 + nt * 16 + l15;
            float hv = h_enc[(size_t)((row0 + m) & (NB - 1)) * HD + t];
            h[nt][v] = hv;
            int off = m * HBS + t;
            split_bf(hv, hhi[off], hlo[off]);
        }
    float b1v[4], b2v[4], gbv[4];
    #pragma unroll
    for (int nt = 0; nt < 4; ++nt) {
        int t = col0 + nt * 16 + l15;
        b1v[nt] = fb1[t]; b2v[nt] = fb2[t]; gbv[nt] = gb[t];
    }
    __syncthreads();

    const float dt = (float)NF / (float)NSTEP;
    const float sqdt = sqrtf(dt);
    const f32x4 zz = {0.f, 0.f, 0.f, 0.f};

    // ---------------- SDE Euler-Maruyama ----------------
    for (int st = 0; st < NSTEP; ++st) {
        float nz[4][4];
        #pragma unroll
        for (int nt = 0; nt < 4; ++nt)
            #pragma unroll
            for (int v = 0; v < 4; ++v) {
                int row = row0 + g4 * 4 + v;
                nz[nt][v] = noise[((size_t)((row >> 7) * NSTEP + st) * NB + (row & (NB - 1))) * HD
                                  + col0 + nt * 16 + l15];
            }
        // phase A: u = tanh(h W1^T + b1)
        f32x4 au[4] = {zz, zz, zz, zz};
        #pragma unroll 2
        for (int kt = 0; kt < 16; ++kt) {
            bf16x8 ah = ld8(&hhi[l15 * HBS + kt * 32 + g4 * 8]);
            bf16x8 al = ld8(&hlo[l15 * HBS + kt * 32 + g4 * 8]);
            #pragma unroll
            for (int nt = 0; nt < 4; ++nt)
                au[nt] = mfma3(ah, al, w1_p + ((size_t)((c16 + nt) * 16 + kt) * 64 + lane) * 16, au[nt]);
        }
        #pragma unroll
        for (int nt = 0; nt < 4; ++nt)
            #pragma unroll
            for (int v = 0; v < 4; ++v) {
                int off = (g4 * 4 + v) * HBS + col0 + nt * 16 + l15;
                split_bf(tanhf(au[nt][v] + b1v[nt]), uhi[off], ulo[off]);
            }
        __syncthreads();  // u ready
        // phase B: f = u W2^T ; g = softplus(h gW^T)
        f32x4 af[4] = {zz, zz, zz, zz};
        f32x4 ag[4] = {zz, zz, zz, zz};
        #pragma unroll 2
        for (int kt = 0; kt < 16; ++kt) {
            bf16x8 ah = ld8(&hhi[l15 * HBS + kt * 32 + g4 * 8]);
            bf16x8 al = ld8(&hlo[l15 * HBS + kt * 32 + g4 * 8]);
            bf16x8 auh = ld8(&uhi[l15 * HBS + kt * 32 + g4 * 8]);
            bf16x8 aul = ld8(&ulo[l15 * HBS + kt * 32 + g4 * 8]);
            #pragma unroll
            for (int nt = 0; nt < 4; ++nt) {
                af[nt] = mfma3(auh, aul, w2_p + ((size_t)((c16 + nt) * 16 + kt) * 64 + lane) * 16, af[nt]);
                ag[nt] = mfma3(ah, al, gw_p + ((size_t)((c16 + nt) * 16 + kt) * 64 + lane) * 16, ag[nt]);
            }
        }
        __syncthreads();  // all h reads done before updates
        #pragma unroll
        for (int nt = 0; nt < 4; ++nt)
            #pragma unroll
            for (int v = 0; v < 4; ++v) {
                float f = af[nt][v] + b2v[nt];
                float g = softp(ag[nt][v] + gbv[nt]);
                h[nt][v] += f * dt + g * sqdt * nz[nt][v];
                int off = (g4 * 4 + v) * HBS + col0 + nt * 16 + l15;
                split_bf(h[nt][v], hhi[off], hlo[off]);
            }
        __syncthreads();  // writes visible before next step
    }

    // ---------------- decoder GRU + out-proj ----------------
    float crv[4], czv[4], binv[4], bhnv[4];
    #pragma unroll
    for (int nt = 0; nt < 4; ++nt) {
        int t = col0 + nt * 16 + l15;
        crv[nt] = dbih[t] + dbhh[t];
        czv[nt] = dbih[HD + t] + dbhh[HD + t];
        binv[nt] = dbih[2 * HD + t];
        bhnv[nt] = dbhh[2 * HD + t];
    }
    float ob = (wv < 2) ? outb[wv * 16 + l15] : 0.0f;

    for (int st = 0; st < NF; ++st) {
        f32x4 ar[4] = {zz, zz, zz, zz};
        f32x4 az[4] = {zz, zz, zz, zz};
        f32x4 anh[4] = {zz, zz, zz, zz};
        #pragma unroll 2
        for (int kt = 0; kt < 16; ++kt) {
            bf16x8 ah = ld8(&hhi[l15 * HBS + kt * 32 + g4 * 8]);
            bf16x8 al = ld8(&hlo[l15 * HBS + kt * 32 + g4 * 8]);
            #pragma unroll
            for (int nt = 0; nt < 4; ++nt) {
                ar[nt]  = mfma3(ah, al, dwhh_p + ((size_t)((0 * 32 + c16 + nt) * 16 + kt) * 64 + lane) * 16, ar[nt]);
                az[nt]  = mfma3(ah, al, dwhh_p + ((size_t)((1 * 32 + c16 + nt) * 16 + kt) * 64 + lane) * 16, az[nt]);
                anh[nt] = mfma3(ah, al, dwhh_p + ((size_t)((2 * 32 + c16 + nt) * 16 + kt) * 64 + lane) * 16, anh[nt]);
            }
        }
        __syncthreads();  // reads done
        #pragma unroll
        for (int nt = 0; nt < 4; ++nt)
            #pragma unroll
            for (int v = 0; v < 4; ++v) {
                float r = sigm(ar[nt][v] + crv[nt]);
                float z = sigm(az[nt][v] + czv[nt]);
                float n = tanhf(binv[nt] + r * (anh[nt][v] + bhnv[nt]));
                h[nt][v] = (1.0f - z) * n + z * h[nt][v];
                int off = (g4 * 4 + v) * HBS + col0 + nt * 16 + l15;
                split_bf(h[nt][v], hhi[off], hlo[off]);
            }
        __syncthreads();  // h updated -> out-proj + next step may read
        if (wv < 2) {
            f32x4 ao = zz;
            #pragma unroll 2
            for (int kt = 0; kt < 16; ++kt) {
                bf16x8 ah = ld8(&hhi[l15 * HBS + kt * 32 + g4 * 8]);
                bf16x8 al = ld8(&hlo[l15 * HBS + kt * 32 + g4 * 8]);
                ao = mfma3(ah, al, outw_p + ((size_t)(wv * 16 + kt) * 64 + lane) * 16, ao);
            }
            #pragma unroll
            for (int v = 0; v < 4; ++v)
                obuf[g4 * 4 + v][wv * 16 + l15][st] = ao[v] + ob;
        }
    }
    __syncthreads();  // obuf complete
    {
        int m = tid >> 5, i = tid & 31;
        int row = row0 + m;  // == s*NB + b
        float4* dst = (float4*)(out + ((size_t)row * NI + i) * NF);
        const float4* src = (const float4*)&obuf[m][i][0];
        #pragma unroll
        for (int q = 0; q < 6; ++q) dst[q] = src[q];
    }
}

extern "C" void kernel_launch(void* const* d_in, const int* in_sizes, int n_in,
                              void* d_out, int out_size, void* d_ws, size_t ws_size,
                              hipStream_t stream) {
    const float* x       = (const float*)d_in[0];
    const float* noise   = (const float*)d_in[1];
    const float* enc_Wih = (const float*)d_in[2];
    const float* enc_Whh = (const float*)d_in[3];
    const float* enc_bih = (const float*)d_in[4];
    const float* enc_bhh = (const float*)d_in[5];
    const float* f_W1    = (const float*)d_in[6];
    const float* f_b1    = (const float*)d_in[7];
    const float* f_W2    = (const float*)d_in[8];
    const float* f_b2    = (const float*)d_in[9];
    const float* g_W     = (const float*)d_in[10];
    const float* g_b     = (const float*)d_in[11];
    const float* dec_Whh = (const float*)d_in[13];
    const float* dec_bih = (const float*)d_in[14];
    const float* dec_bhh = (const float*)d_in[15];
    const float* out_W   = (const float*)d_in[16];
    const float* out_b   = (const float*)d_in[17];
    float* out = (float*)d_out;

    char* ws = (char*)d_ws;
    float*          h_enc  = (float*)(ws + 0);                   // 256 KB
    unsigned short* whh_p  = (unsigned short*)(ws + 262144);     // 3 MB
    unsigned short* wih_p  = (unsigned short*)(ws + 3407872);    // 192 KB
    unsigned short* w1_p   = (unsigned short*)(ws + 3604480);    // 1 MB
    unsigned short* w2_p   = (unsigned short*)(ws + 4653056);    // 1 MB
    unsigned short* gw_p   = (unsigned short*)(ws + 5701632);    // 1 MB
    unsigned short* dwhh_p = (unsigned short*)(ws + 6750208);    // 3 MB
    unsigned short* outw_p = (unsigned short*)(ws + 9895936);    // 64 KB
    unsigned short* xt_hi  = (unsigned short*)(ws + 9961472);    // 768 KB
    unsigned short* xt_lo  = (unsigned short*)(ws + 10747904);   // 768 KB

    pack_w<<<384, 256, 0, stream>>>(enc_Whh, whh_p, 3 * HD, HD);
    pack_w<<<24, 256, 0, stream>>>(enc_Wih, wih_p, 3 * HD, NI);
    pack_w<<<128, 256, 0, stream>>>(f_W1, w1_p, HD, HD);
    pack_w<<<128, 256, 0, stream>>>(f_W2, w2_p, HD, HD);
    pack_w<<<128, 256, 0, stream>>>(g_W, gw_p, HD, HD);
    pack_w<<<384, 256, 0, stream>>>(dec_Whh, dwhh_p, 3 * HD, HD);
    pack_w<<<8, 256, 0, stream>>>(out_W, outw_p, NI, HD);
    pack_x<<<48, 256, 0, stream>>>(x, xt_hi, xt_lo);

    enc_mfma<<<8, 512, 0, stream>>>(xt_hi, xt_lo, wih_p, whh_p, enc_bih, enc_bhh, h_enc);
    sde_dec_mfma<<<NS * NB / 16, 512, 0, stream>>>(
        h_enc, noise, w1_p, w2_p, gw_p, dwhh_p, outw_p,
        f_b1, f_b2, g_b, dec_bih, dec_bhh, out_b, out);
}

// Round 4
// 3725.643 us; speedup vs baseline: 4.6759x; 1.3138x over previous
//
#include <hip/hip_runtime.h>
#include <math.h>

typedef __bf16 bf16x8 __attribute__((ext_vector_type(8)));
typedef float f32x4 __attribute__((ext_vector_type(4)));

#define HD 512
#define NB 128
#define NI 32
#define NL 96
#define NS 16
#define NF 24
#define NSTEP 23

#define MFMA16(a,b,c) __builtin_amdgcn_mfma_f32_16x16x32_bf16(a,b,c,0,0,0)

__device__ __forceinline__ unsigned short f2bf(float f) {
    union { float f; unsigned u; } v; v.f = f;
    unsigned r = v.u + 0x7fffu + ((v.u >> 16) & 1u);
    return (unsigned short)(r >> 16);
}
__device__ __forceinline__ float bf2f(unsigned short h) {
    union { unsigned u; float f; } v; v.u = ((unsigned)h) << 16;
    return v.f;
}
__device__ __forceinline__ void split_bf(float v, unsigned short& hi, unsigned short& lo) {
    unsigned short h = f2bf(v);
    hi = h;
    lo = f2bf(v - bf2f(h));
}
__device__ __forceinline__ float sigm(float x) { return 1.0f / (1.0f + __expf(-x)); }
__device__ __forceinline__ float softp(float x) {
    return fmaxf(x, 0.0f) + log1pf(__expf(-fabsf(x)));
}
__device__ __forceinline__ bf16x8 ld8(const unsigned short* p) {
    return *reinterpret_cast<const bf16x8*>(p);
}
__device__ __forceinline__ f32x4 mfma3(bf16x8 ahi, bf16x8 alo, const unsigned short* bp, f32x4 c) {
    bf16x8 bhi = ld8(bp);
    bf16x8 blo = ld8(bp + 8);
    c = MFMA16(ahi, bhi, c);
    c = MFMA16(alo, bhi, c);
    c = MFMA16(ahi, blo, c);
    return c;
}
__device__ __forceinline__ void ldfrag(const unsigned short* __restrict__ base, size_t idx,
                                       bf16x8& hi, bf16x8& lo) {
    const unsigned short* p = base + idx * 16;
    hi = ld8(p);
    lo = ld8(p + 8);
}
// group barrier: monotonic counter, agent-scope atomics, works across XCDs
__device__ __forceinline__ void gbar(unsigned* ctr, unsigned target) {
    __syncthreads();
    if (threadIdx.x == 0) {
        __threadfence();
        __hip_atomic_fetch_add(ctr, 1u, __ATOMIC_RELAXED, __HIP_MEMORY_SCOPE_AGENT);
        while (__hip_atomic_load(ctr, __ATOMIC_RELAXED, __HIP_MEMORY_SCOPE_AGENT) < target)
            __builtin_amdgcn_s_sleep(2);
        __threadfence();
    }
    __syncthreads();
}

// ---------- prep: pack W[N][K] fp32 -> split bf16 B-fragments ----------
__global__ void pack_w(const float* __restrict__ W, unsigned short* __restrict__ Wp,
                       int N, int K) {
    int idx = blockIdx.x * 256 + threadIdx.x;
    int total = (N / 16) * (K / 32) * 64;
    if (idx >= total) return;
    int lane = idx & 63;
    int t2 = idx >> 6;
    int KT = K / 32;
    int kt = t2 % KT, nt = t2 / KT;
    const float* src = W + (size_t)(nt * 16 + (lane & 15)) * K + kt * 32 + (lane >> 4) * 8;
    unsigned short* dst = Wp + (size_t)idx * 16;
    #pragma unroll
    for (int j = 0; j < 8; ++j) split_bf(src[j], dst[j], dst[8 + j]);
}

// ---------- prep: x[B][I][L] fp32 -> xhi/xlo [L][B][I] bf16 ----------
__global__ void pack_x(const float* __restrict__ x, unsigned short* __restrict__ xhi,
                       unsigned short* __restrict__ xlo) {
    int idx = blockIdx.x * 256 + threadIdx.x;
    if (idx >= NL * NB) return;
    int b = idx % NB, l = idx / NB;
    size_t base = (size_t)(l * NB + b) * NI;
    #pragma unroll
    for (int i = 0; i < NI; ++i)
        split_bf(x[((size_t)b * NI + i) * NL + l], xhi[base + i], xlo[base + i]);
}

// =================== fused cooperative kernel ===================
__global__ __launch_bounds__(512) void coop_all(
    const unsigned short* __restrict__ xhi, const unsigned short* __restrict__ xlo,
    const unsigned short* __restrict__ wih_p, const unsigned short* __restrict__ whh_p,
    const unsigned short* __restrict__ w1_p, const unsigned short* __restrict__ w2_p,
    const unsigned short* __restrict__ gw_p, const unsigned short* __restrict__ dwhh_p,
    const unsigned short* __restrict__ outw_p,
    const float* __restrict__ ebih, const float* __restrict__ ebhh,
    const float* __restrict__ fb1, const float* __restrict__ fb2,
    const float* __restrict__ gb, const float* __restrict__ dbih,
    const float* __restrict__ dbhh, const float* __restrict__ outb,
    const float* __restrict__ noise,
    unsigned short* hE0, unsigned short* hE1,
    unsigned short* hP0, unsigned short* hP1, unsigned short* uP,
    float* h_encF, float* out, unsigned* bar)
{
    const int bid = blockIdx.x;
    const int tid = threadIdx.x, lane = tid & 63, wv = tid >> 6;
    const int l15 = lane & 15, g4 = lane >> 4;
    const f32x4 zz = {0.f, 0.f, 0.f, 0.f};

    __shared__ float pred[4][8][16][16];
    __shared__ __align__(16) unsigned short Thi[128][32];
    __shared__ __align__(16) unsigned short Tlo[128][32];

    // =============== encoder: group g = m-tile (16 rows), slice n = 16 units ===============
    {
        const int g = bid & 7, n = bid >> 3;
        unsigned* ctr = bar + (1 + g) * 16;
        float hcell = 0.f;
        float cr = 0.f, cz = 0.f, binx = 0.f, bhnn = 0.f;
        const int crow = tid >> 4, cunit = tid & 15;
        if (tid < 256) {
            int u = n * 16 + cunit;
            cr = ebih[u] + ebhh[u];
            cz = ebih[HD + u] + ebhh[HD + u];
            binx = ebih[2 * HD + u];
            bhnn = ebhh[2 * HD + u];
        }
        unsigned short* hEbuf[2] = {hE0, hE1};
        #pragma unroll 1
        for (int l = 0; l < NL; ++l) {
            const unsigned short* cur = hEbuf[l & 1];
            unsigned short* nxt = hEbuf[(l & 1) ^ 1];
            f32x4 pr = zz, pz = zz, pnh = zz, pnx = zz;
            if (wv == 0) {
                size_t xb = (size_t)(l * NB + g * 16 + l15) * NI + g4 * 8;
                bf16x8 axh = ld8(xhi + xb), axl = ld8(xlo + xb);
                pr  = mfma3(axh, axl, wih_p + ((size_t)(0 * 32 + n) * 64 + lane) * 16, pr);
                pz  = mfma3(axh, axl, wih_p + ((size_t)(1 * 32 + n) * 64 + lane) * 16, pz);
                pnx = mfma3(axh, axl, wih_p + ((size_t)(2 * 32 + n) * 64 + lane) * 16, pnx);
            }
            #pragma unroll
            for (int kk = 0; kk < 2; ++kk) {
                int kt = wv * 2 + kk;
                bf16x8 ah, al;
                ldfrag(cur, (size_t)(g * 16 + kt) * 64 + lane, ah, al);
                pr  = mfma3(ah, al, whh_p + ((size_t)((0 * 32 + n) * 16 + kt) * 64 + lane) * 16, pr);
                pz  = mfma3(ah, al, whh_p + ((size_t)((1 * 32 + n) * 16 + kt) * 64 + lane) * 16, pz);
                pnh = mfma3(ah, al, whh_p + ((size_t)((2 * 32 + n) * 16 + kt) * 64 + lane) * 16, pnh);
            }
            #pragma unroll
            for (int v = 0; v < 4; ++v) {
                pred[0][wv][g4 * 4 + v][l15] = pr[v];
                pred[1][wv][g4 * 4 + v][l15] = pz[v];
                pred[2][wv][g4 * 4 + v][l15] = pnh[v];
                if (wv == 0) pred[3][0][g4 * 4 + v][l15] = pnx[v];
            }
            __syncthreads();
            if (tid < 256) {
                float ar = 0.f, az = 0.f, anh_ = 0.f;
                #pragma unroll
                for (int w = 0; w < 8; ++w) {
                    ar += pred[0][w][crow][cunit];
                    az += pred[1][w][crow][cunit];
                    anh_ += pred[2][w][crow][cunit];
                }
                float anx_ = pred[3][0][crow][cunit];
                float r = sigm(ar + cr);
                float z = sigm(az + cz);
                float nn = tanhf(anx_ + binx + r * (anh_ + bhnn));
                hcell = (1.f - z) * nn + z * hcell;
                unsigned short hi, lo;
                split_bf(hcell, hi, lo);
                Thi[crow][cunit] = hi;
                Tlo[crow][cunit] = lo;
                if (l == NL - 1)
                    h_encF[(size_t)(g * 16 + crow) * HD + n * 16 + cunit] = hcell;
            }
            __syncthreads();
            if (tid < 32) {
                int half = n & 1, kt = n >> 1;
                int lp = half * 32 + tid;
                bf16x8 vh = *(const bf16x8*)&Thi[tid & 15][(tid >> 4) * 8];
                bf16x8 vl = *(const bf16x8*)&Tlo[tid & 15][(tid >> 4) * 8];
                unsigned short* dst = nxt + ((size_t)(g * 16 + kt) * 64 + lp) * 16;
                *(bf16x8*)dst = vh;
                *(bf16x8*)(dst + 8) = vl;
            }
            gbar(ctr, 32u * (l + 1));
        }
    }

    // full-grid barrier: h_encF + final frags (in hE0) visible to everyone
    gbar(bar, 256u);

    // =============== SDE + decoder: group g2 = sample (128 rows), slice n2 = 32 units ===============
    const int g2 = (bid & 7) * 2 + ((bid >> 3) & 1);
    const int n2 = bid >> 4;
    unsigned* ctr2 = bar + (9 + g2) * 16;
    const float dt = (float)NF / (float)NSTEP;
    const float sqdt = sqrtf(dt);

    float hreg[2][4];
    #pragma unroll
    for (int nt = 0; nt < 2; ++nt)
        #pragma unroll
        for (int v = 0; v < 4; ++v)
            hreg[nt][v] = h_encF[(size_t)(wv * 16 + g4 * 4 + v) * HD + n2 * 32 + nt * 16 + l15];

    float b1v[2], b2v[2], gbv[2];
    #pragma unroll
    for (int nt = 0; nt < 2; ++nt) {
        int u = n2 * 32 + nt * 16 + l15;
        b1v[nt] = fb1[u]; b2v[nt] = fb2[u]; gbv[nt] = gb[u];
    }

    unsigned short* hPb[2] = {hP0, hP1};
    int cur = 0;

    #pragma unroll 1
    for (int st = 0; st < NSTEP; ++st) {
        const unsigned short* hsrc = (st == 0) ? hE0 : hPb[cur];
        const int mtbase = (st == 0) ? wv : (g2 * 8 + wv);
        // ---- phase A: u = tanh(h W1^T + b1) ----
        f32x4 au[2] = {zz, zz};
        #pragma unroll 2
        for (int kt = 0; kt < 16; ++kt) {
            bf16x8 ah, al;
            ldfrag(hsrc, (size_t)(mtbase * 16 + kt) * 64 + lane, ah, al);
            #pragma unroll
            for (int nt = 0; nt < 2; ++nt)
                au[nt] = mfma3(ah, al, w1_p + ((size_t)((n2 * 2 + nt) * 16 + kt) * 64 + lane) * 16, au[nt]);
        }
        #pragma unroll
        for (int nt = 0; nt < 2; ++nt)
            #pragma unroll
            for (int v = 0; v < 4; ++v) {
                unsigned short hi, lo;
                split_bf(tanhf(au[nt][v] + b1v[nt]), hi, lo);
                Thi[wv * 16 + g4 * 4 + v][nt * 16 + l15] = hi;
                Tlo[wv * 16 + g4 * 4 + v][nt * 16 + l15] = lo;
            }
        __syncthreads();
        {
            int mt = tid >> 6, ln = tid & 63;
            bf16x8 vh = *(const bf16x8*)&Thi[mt * 16 + (ln & 15)][(ln >> 4) * 8];
            bf16x8 vl = *(const bf16x8*)&Tlo[mt * 16 + (ln & 15)][(ln >> 4) * 8];
            unsigned short* dst = uP + ((size_t)((g2 * 8 + mt) * 16 + n2) * 64 + ln) * 16;
            *(bf16x8*)dst = vh;
            *(bf16x8*)(dst + 8) = vl;
        }
        gbar(ctr2, 16u * (2 * st + 1));
        // ---- phase B: f = u W2^T + b2 ; g = softplus(h gW^T + gb) ----
        f32x4 af[2] = {zz, zz}, ag[2] = {zz, zz};
        #pragma unroll 2
        for (int kt = 0; kt < 16; ++kt) {
            bf16x8 ah, al, uh, ul;
            ldfrag(hsrc, (size_t)(mtbase * 16 + kt) * 64 + lane, ah, al);
            ldfrag(uP, (size_t)((g2 * 8 + wv) * 16 + kt) * 64 + lane, uh, ul);
            #pragma unroll
            for (int nt = 0; nt < 2; ++nt) {
                af[nt] = mfma3(uh, ul, w2_p + ((size_t)((n2 * 2 + nt) * 16 + kt) * 64 + lane) * 16, af[nt]);
                ag[nt] = mfma3(ah, al, gw_p + ((size_t)((n2 * 2 + nt) * 16 + kt) * 64 + lane) * 16, ag[nt]);
            }
        }
        #pragma unroll
        for (int nt = 0; nt < 2; ++nt)
            #pragma unroll
            for (int v = 0; v < 4; ++v) {
                int b = wv * 16 + g4 * 4 + v;
                float nz = noise[((size_t)(g2 * NSTEP + st) * NB + b) * HD + n2 * 32 + nt * 16 + l15];
                float f = af[nt][v] + b2v[nt];
                float gg = softp(ag[nt][v] + gbv[nt]);
                hreg[nt][v] += f * dt + gg * sqdt * nz;
                unsigned short hi, lo;
                split_bf(hreg[nt][v], hi, lo);
                Thi[b][nt * 16 + l15] = hi;
                Tlo[b][nt * 16 + l15] = lo;
            }
        __syncthreads();
        {
            int mt = tid >> 6, ln = tid & 63;
            bf16x8 vh = *(const bf16x8*)&Thi[mt * 16 + (ln & 15)][(ln >> 4) * 8];
            bf16x8 vl = *(const bf16x8*)&Tlo[mt * 16 + (ln & 15)][(ln >> 4) * 8];
            unsigned short* dst = hPb[cur ^ 1] + ((size_t)((g2 * 8 + mt) * 16 + n2) * 64 + ln) * 16;
            *(bf16x8*)dst = vh;
            *(bf16x8*)(dst + 8) = vl;
        }
        cur ^= 1;
        gbar(ctr2, 16u * (2 * st + 2));
    }

    // =============== decoder GRU + out-proj ===============
    float crv[2], czv[2], binv[2], bhnv[2];
    #pragma unroll
    for (int nt = 0; nt < 2; ++nt) {
        int u = n2 * 32 + nt * 16 + l15;
        crv[nt] = dbih[u] + dbhh[u];
        czv[nt] = dbih[HD + u] + dbhh[HD + u];
        binv[nt] = dbih[2 * HD + u];
        bhnv[nt] = dbhh[2 * HD + u];
    }
    const float obias = (n2 < 2) ? outb[n2 * 16 + l15] : 0.f;

    #pragma unroll 1
    for (int j = 0; j <= NF; ++j) {
        const unsigned short* hsrc = hPb[cur];
        f32x4 ar[2] = {zz, zz}, az2[2] = {zz, zz}, anh[2] = {zz, zz}, ao = zz;
        if (j < NF || n2 < 2) {
            #pragma unroll 2
            for (int kt = 0; kt < 16; ++kt) {
                bf16x8 ah, al;
                ldfrag(hsrc, (size_t)((g2 * 8 + wv) * 16 + kt) * 64 + lane, ah, al);
                if (j < NF) {
                    #pragma unroll
                    for (int nt = 0; nt < 2; ++nt) {
                        int nn = n2 * 2 + nt;
                        ar[nt]  = mfma3(ah, al, dwhh_p + ((size_t)((0 * 32 + nn) * 16 + kt) * 64 + lane) * 16, ar[nt]);
                        az2[nt] = mfma3(ah, al, dwhh_p + ((size_t)((1 * 32 + nn) * 16 + kt) * 64 + lane) * 16, az2[nt]);
                        anh[nt] = mfma3(ah, al, dwhh_p + ((size_t)((2 * 32 + nn) * 16 + kt) * 64 + lane) * 16, anh[nt]);
                    }
                }
                if (j >= 1 && n2 < 2)
                    ao = mfma3(ah, al, outw_p + ((size_t)(n2 * 16 + kt) * 64 + lane) * 16, ao);
            }
        }
        if (j >= 1 && n2 < 2) {
            #pragma unroll
            for (int v = 0; v < 4; ++v) {
                int b = wv * 16 + g4 * 4 + v;
                out[(((size_t)g2 * NB + b) * NI + (n2 * 16 + l15)) * NF + (j - 1)] = ao[v] + obias;
            }
        }
        if (j < NF) {
            #pragma unroll
            for (int nt = 0; nt < 2; ++nt)
                #pragma unroll
                for (int v = 0; v < 4; ++v) {
                    int b = wv * 16 + g4 * 4 + v;
                    float r = sigm(ar[nt][v] + crv[nt]);
                    float z = sigm(az2[nt][v] + czv[nt]);
                    float nn2 = tanhf(binv[nt] + r * (anh[nt][v] + bhnv[nt]));
                    hreg[nt][v] = (1.f - z) * nn2 + z * hreg[nt][v];
                    unsigned short hi, lo;
                    split_bf(hreg[nt][v], hi, lo);
                    Thi[b][nt * 16 + l15] = hi;
                    Tlo[b][nt * 16 + l15] = lo;
                }
            __syncthreads();
            {
                int mt = tid >> 6, ln = tid & 63;
                bf16x8 vh = *(const bf16x8*)&Thi[mt * 16 + (ln & 15)][(ln >> 4) * 8];
                bf16x8 vl = *(const bf16x8*)&Tlo[mt * 16 + (ln & 15)][(ln >> 4) * 8];
                unsigned short* dst = hPb[cur ^ 1] + ((size_t)((g2 * 8 + mt) * 16 + n2) * 64 + ln) * 16;
                *(bf16x8*)dst = vh;
                *(bf16x8*)(dst + 8) = vl;
            }
            cur ^= 1;
        }
        gbar(ctr2, 16u * (2 * NSTEP + j + 1));
    }
}

extern "C" void kernel_launch(void* const* d_in, const int* in_sizes, int n_in,
                              void* d_out, int out_size, void* d_ws, size_t ws_size,
                              hipStream_t stream) {
    const float* x       = (const float*)d_in[0];
    const float* noise   = (const float*)d_in[1];
    const float* enc_Wih = (const float*)d_in[2];
    const float* enc_Whh = (const float*)d_in[3];
    const float* enc_bih = (const float*)d_in[4];
    const float* enc_bhh = (const float*)d_in[5];
    const float* f_W1    = (const float*)d_in[6];
    const float* f_b1    = (const float*)d_in[7];
    const float* f_W2    = (const float*)d_in[8];
    const float* f_b2    = (const float*)d_in[9];
    const float* g_W     = (const float*)d_in[10];
    const float* g_b     = (const float*)d_in[11];
    const float* dec_Whh = (const float*)d_in[13];
    const float* dec_bih = (const float*)d_in[14];
    const float* dec_bhh = (const float*)d_in[15];
    const float* out_W   = (const float*)d_in[16];
    const float* out_b   = (const float*)d_in[17];
    float* out = (float*)d_out;

    char* ws = (char*)d_ws;
    unsigned short* whh_p  = (unsigned short*)(ws + 0);          // 3 MB
    unsigned short* wih_p  = (unsigned short*)(ws + 3145728);    // 192 KB
    unsigned short* w1_p   = (unsigned short*)(ws + 3342336);    // 1 MB
    unsigned short* w2_p   = (unsigned short*)(ws + 4390912);    // 1 MB
    unsigned short* gw_p   = (unsigned short*)(ws + 5439488);    // 1 MB
    unsigned short* dwhh_p = (unsigned short*)(ws + 6488064);    // 3 MB
    unsigned short* outw_p = (unsigned short*)(ws + 9633792);    // 64 KB
    unsigned short* xhi    = (unsigned short*)(ws + 9699328);    // 768 KB
    unsigned short* xlo    = (unsigned short*)(ws + 10485760);   // 768 KB
    unsigned short* hE1    = (unsigned short*)(ws + 11272192);   // 256 KB
    unsigned short* hP0    = (unsigned short*)(ws + 11534336);   // 4 MB
    unsigned short* hP1    = (unsigned short*)(ws + 15728640);   // 4 MB
    unsigned short* uP     = (unsigned short*)(ws + 19922944);   // 4 MB
    float*          h_encF = (float*)(ws + 24117248);            // 256 KB
    unsigned*       bar    = (unsigned*)(ws + 24379392);         // 2 KB
    unsigned short* hE0    = (unsigned short*)(ws + 24381440);   // 256 KB (contiguous w/ bar for one memset)

    // zero barrier counters + initial encoder h fragments
    hipMemsetAsync(ws + 24379392, 0, 2048 + 262144, stream);

    pack_w<<<384, 256, 0, stream>>>(enc_Whh, whh_p, 3 * HD, HD);
    pack_w<<<24, 256, 0, stream>>>(enc_Wih, wih_p, 3 * HD, NI);
    pack_w<<<128, 256, 0, stream>>>(f_W1, w1_p, HD, HD);
    pack_w<<<128, 256, 0, stream>>>(f_W2, w2_p, HD, HD);
    pack_w<<<128, 256, 0, stream>>>(g_W, gw_p, HD, HD);
    pack_w<<<384, 256, 0, stream>>>(dec_Whh, dwhh_p, 3 * HD, HD);
    pack_w<<<8, 256, 0, stream>>>(out_W, outw_p, NI, HD);
    pack_x<<<48, 256, 0, stream>>>(x, xhi, xlo);

    void* args[] = {
        (void*)&xhi, (void*)&xlo, (void*)&wih_p, (void*)&whh_p,
        (void*)&w1_p, (void*)&w2_p, (void*)&gw_p, (void*)&dwhh_p, (void*)&outw_p,
        (void*)&enc_bih, (void*)&enc_bhh, (void*)&f_b1, (void*)&f_b2,
        (void*)&g_b, (void*)&dec_bih, (void*)&dec_bhh, (void*)&out_b,
        (void*)&noise,
        (void*)&hE0, (void*)&hE1, (void*)&hP0, (void*)&hP1, (void*)&uP,
        (void*)&h_encF, (void*)&out, (void*)&bar
    };
    hipLaunchCooperativeKernel((void*)coop_all, dim3(256), dim3(512), args, 0, stream);
}

// Round 5
// 2555.000 us; speedup vs baseline: 6.8183x; 1.4582x over previous
//
#include <hip/hip_runtime.h>
#include <math.h>

typedef __bf16 bf16x8 __attribute__((ext_vector_type(8)));
typedef float f32x4 __attribute__((ext_vector_type(4)));
typedef unsigned long long u64;

#define HD 512
#define NB 128
#define NI 32
#define NL 96
#define NS 16
#define NF 24
#define NSTEP 23
#define TS 40   // padded LDS transpose stride (shorts): 80 B rows, 16B-aligned, 2-way max conflict

#define MFMA16(a,b,c) __builtin_amdgcn_mfma_f32_16x16x32_bf16(a,b,c,0,0,0)

__device__ __forceinline__ unsigned short f2bf(float f) {
    union { float f; unsigned u; } v; v.f = f;
    unsigned r = v.u + 0x7fffu + ((v.u >> 16) & 1u);
    return (unsigned short)(r >> 16);
}
__device__ __forceinline__ float bf2f(unsigned short h) {
    union { unsigned u; float f; } v; v.u = ((unsigned)h) << 16;
    return v.f;
}
__device__ __forceinline__ void split_bf(float v, unsigned short& hi, unsigned short& lo) {
    unsigned short h = f2bf(v);
    hi = h;
    lo = f2bf(v - bf2f(h));
}
__device__ __forceinline__ float sigm(float x) { return 1.0f / (1.0f + __expf(-x)); }
__device__ __forceinline__ float softp(float x) {
    return fmaxf(x, 0.0f) + log1pf(__expf(-fabsf(x)));
}
__device__ __forceinline__ bf16x8 ld8(const unsigned short* p) {
    return *reinterpret_cast<const bf16x8*>(p);
}
__device__ __forceinline__ f32x4 mfma3(bf16x8 ahi, bf16x8 alo, const unsigned short* bp, f32x4 c) {
    bf16x8 bhi = ld8(bp);
    bf16x8 blo = ld8(bp + 8);
    c = MFMA16(ahi, bhi, c);
    c = MFMA16(alo, bhi, c);
    c = MFMA16(ahi, blo, c);
    return c;
}

// ---- device-coherent state exchange: relaxed agent-scope 8B atomics (no fences!) ----
__device__ __forceinline__ void st_frag(unsigned short* dst, bf16x8 hi, bf16x8 lo) {
    union { bf16x8 v; u64 q[2]; } h, l;
    h.v = hi; l.v = lo;
    u64* d = (u64*)dst;
    __hip_atomic_store(d + 0, h.q[0], __ATOMIC_RELAXED, __HIP_MEMORY_SCOPE_AGENT);
    __hip_atomic_store(d + 1, h.q[1], __ATOMIC_RELAXED, __HIP_MEMORY_SCOPE_AGENT);
    __hip_atomic_store(d + 2, l.q[0], __ATOMIC_RELAXED, __HIP_MEMORY_SCOPE_AGENT);
    __hip_atomic_store(d + 3, l.q[1], __ATOMIC_RELAXED, __HIP_MEMORY_SCOPE_AGENT);
}
__device__ __forceinline__ void ld_frag(const unsigned short* src, bf16x8& hi, bf16x8& lo) {
    u64* s = (u64*)src;
    union { bf16x8 v; u64 q[2]; } h, l;
    h.q[0] = __hip_atomic_load(s + 0, __ATOMIC_RELAXED, __HIP_MEMORY_SCOPE_AGENT);
    h.q[1] = __hip_atomic_load(s + 1, __ATOMIC_RELAXED, __HIP_MEMORY_SCOPE_AGENT);
    l.q[0] = __hip_atomic_load(s + 2, __ATOMIC_RELAXED, __HIP_MEMORY_SCOPE_AGENT);
    l.q[1] = __hip_atomic_load(s + 3, __ATOMIC_RELAXED, __HIP_MEMORY_SCOPE_AGENT);
    hi = h.v; lo = l.v;
}
// barrier: drain own vmem, block-barrier (drains all threads), relaxed counter, spin.
// No __threadfence -> no L2 writeback/invalidate -> weights stay L2-resident.
__device__ __forceinline__ void gbar(unsigned* ctr, unsigned target) {
    __builtin_amdgcn_s_waitcnt(0);
    __syncthreads();
    if (threadIdx.x == 0) {
        __hip_atomic_fetch_add(ctr, 1u, __ATOMIC_RELAXED, __HIP_MEMORY_SCOPE_AGENT);
        while (__hip_atomic_load(ctr, __ATOMIC_RELAXED, __HIP_MEMORY_SCOPE_AGENT) < target)
            __builtin_amdgcn_s_sleep(2);
    }
    __syncthreads();
}

// ---------- prep: pack W[N][K] fp32 -> split bf16 B-fragments ----------
__global__ void pack_w(const float* __restrict__ W, unsigned short* __restrict__ Wp,
                       int N, int K) {
    int idx = blockIdx.x * 256 + threadIdx.x;
    int total = (N / 16) * (K / 32) * 64;
    if (idx >= total) return;
    int lane = idx & 63;
    int t2 = idx >> 6;
    int KT = K / 32;
    int kt = t2 % KT, nt = t2 / KT;
    const float* src = W + (size_t)(nt * 16 + (lane & 15)) * K + kt * 32 + (lane >> 4) * 8;
    unsigned short* dst = Wp + (size_t)idx * 16;
    #pragma unroll
    for (int j = 0; j < 8; ++j) split_bf(src[j], dst[j], dst[8 + j]);
}

// ---------- prep: x[B][I][L] fp32 -> xhi/xlo [L][B][I] bf16 ----------
__global__ void pack_x(const float* __restrict__ x, unsigned short* __restrict__ xhi,
                       unsigned short* __restrict__ xlo) {
    int idx = blockIdx.x * 256 + threadIdx.x;
    if (idx >= NL * NB) return;
    int b = idx % NB, l = idx / NB;
    size_t base = (size_t)(l * NB + b) * NI;
    #pragma unroll
    for (int i = 0; i < NI; ++i)
        split_bf(x[((size_t)b * NI + i) * NL + l], xhi[base + i], xlo[base + i]);
}

// =================== fused cooperative kernel ===================
__global__ __launch_bounds__(512) void coop_all(
    const unsigned short* __restrict__ xhi, const unsigned short* __restrict__ xlo,
    const unsigned short* __restrict__ wih_p, const unsigned short* __restrict__ whh_p,
    const unsigned short* __restrict__ w1_p, const unsigned short* __restrict__ w2_p,
    const unsigned short* __restrict__ gw_p, const unsigned short* __restrict__ dwhh_p,
    const unsigned short* __restrict__ outw_p,
    const float* __restrict__ ebih, const float* __restrict__ ebhh,
    const float* __restrict__ fb1, const float* __restrict__ fb2,
    const float* __restrict__ gb, const float* __restrict__ dbih,
    const float* __restrict__ dbhh, const float* __restrict__ outb,
    const float* __restrict__ noise,
    unsigned short* hE0, unsigned short* hE1,
    unsigned short* hP0, unsigned short* hP1, unsigned short* uP,
    unsigned* h_encF, float* out, unsigned* bar)
{
    const int bid = blockIdx.x;
    const int tid = threadIdx.x, lane = tid & 63, wv = tid >> 6;
    const int l15 = lane & 15, g4 = lane >> 4;
    const f32x4 zz = {0.f, 0.f, 0.f, 0.f};

    __shared__ float pred[4][8][16][16];
    __shared__ __align__(16) unsigned short Thi[128][TS];
    __shared__ __align__(16) unsigned short Tlo[128][TS];

    // =============== encoder: group g = m-tile (16 rows), slice n = 16 units ===============
    {
        const int g = bid & 7, n = bid >> 3;
        unsigned* ctr = bar + (1 + g) * 16;
        float hcell = 0.f;
        float cr = 0.f, cz = 0.f, binx = 0.f, bhnn = 0.f;
        const int crow = tid >> 4, cunit = tid & 15;
        if (tid < 256) {
            int u = n * 16 + cunit;
            cr = ebih[u] + ebhh[u];
            cz = ebih[HD + u] + ebhh[HD + u];
            binx = ebih[2 * HD + u];
            bhnn = ebhh[2 * HD + u];
        }
        unsigned short* hEbuf[2] = {hE0, hE1};
        #pragma unroll 1
        for (int l = 0; l < NL; ++l) {
            const unsigned short* cur = hEbuf[l & 1];
            unsigned short* nxt = hEbuf[(l & 1) ^ 1];
            f32x4 pr = zz, pz = zz, pnh = zz, pnx = zz;
            if (wv == 0) {
                size_t xb = (size_t)(l * NB + g * 16 + l15) * NI + g4 * 8;
                bf16x8 axh = ld8(xhi + xb), axl = ld8(xlo + xb);
                pr  = mfma3(axh, axl, wih_p + ((size_t)(0 * 32 + n) * 64 + lane) * 16, pr);
                pz  = mfma3(axh, axl, wih_p + ((size_t)(1 * 32 + n) * 64 + lane) * 16, pz);
                pnx = mfma3(axh, axl, wih_p + ((size_t)(2 * 32 + n) * 64 + lane) * 16, pnx);
            }
            #pragma unroll
            for (int kk = 0; kk < 2; ++kk) {
                int kt = wv * 2 + kk;
                bf16x8 ah, al;
                ld_frag(cur + ((size_t)(g * 16 + kt) * 64 + lane) * 16, ah, al);
                pr  = mfma3(ah, al, whh_p + ((size_t)((0 * 32 + n) * 16 + kt) * 64 + lane) * 16, pr);
                pz  = mfma3(ah, al, whh_p + ((size_t)((1 * 32 + n) * 16 + kt) * 64 + lane) * 16, pz);
                pnh = mfma3(ah, al, whh_p + ((size_t)((2 * 32 + n) * 16 + kt) * 64 + lane) * 16, pnh);
            }
            #pragma unroll
            for (int v = 0; v < 4; ++v) {
                pred[0][wv][g4 * 4 + v][l15] = pr[v];
                pred[1][wv][g4 * 4 + v][l15] = pz[v];
                pred[2][wv][g4 * 4 + v][l15] = pnh[v];
                if (wv == 0) pred[3][0][g4 * 4 + v][l15] = pnx[v];
            }
            __syncthreads();
            if (tid < 256) {
                float ar = 0.f, az = 0.f, anh_ = 0.f;
                #pragma unroll
                for (int w = 0; w < 8; ++w) {
                    ar += pred[0][w][crow][cunit];
                    az += pred[1][w][crow][cunit];
                    anh_ += pred[2][w][crow][cunit];
                }
                float anx_ = pred[3][0][crow][cunit];
                float r = sigm(ar + cr);
                float z = sigm(az + cz);
                float nn = tanhf(anx_ + binx + r * (anh_ + bhnn));
                hcell = (1.f - z) * nn + z * hcell;
                unsigned short hi, lo;
                split_bf(hcell, hi, lo);
                Thi[crow][cunit] = hi;
                Tlo[crow][cunit] = lo;
                if (l == NL - 1)
                    __hip_atomic_store(h_encF + (size_t)(g * 16 + crow) * HD + n * 16 + cunit,
                                       __float_as_uint(hcell),
                                       __ATOMIC_RELAXED, __HIP_MEMORY_SCOPE_AGENT);
            }
            __syncthreads();
            if (tid < 32) {
                int half = n & 1, kt = n >> 1;
                int lp = half * 32 + tid;
                bf16x8 vh = *(const bf16x8*)&Thi[tid & 15][(tid >> 4) * 8];
                bf16x8 vl = *(const bf16x8*)&Tlo[tid & 15][(tid >> 4) * 8];
                st_frag(nxt + ((size_t)(g * 16 + kt) * 64 + lp) * 16, vh, vl);
            }
            gbar(ctr, 32u * (l + 1));
        }
    }

    // full-grid barrier: h_encF + final frags (hE0) written with agent atomics -> visible
    gbar(bar, 256u);

    // =============== SDE + decoder: group g2 = sample (128 rows), slice n2 = 32 units ===============
    const int g2 = (bid & 7) * 2 + ((bid >> 3) & 1);
    const int n2 = bid >> 4;
    unsigned* ctr2 = bar + (9 + g2) * 16;
    const float dt = (float)NF / (float)NSTEP;
    const float sqdt = sqrtf(dt);

    float hreg[2][4];
    #pragma unroll
    for (int nt = 0; nt < 2; ++nt)
        #pragma unroll
        for (int v = 0; v < 4; ++v)
            hreg[nt][v] = __uint_as_float(__hip_atomic_load(
                h_encF + (size_t)(wv * 16 + g4 * 4 + v) * HD + n2 * 32 + nt * 16 + l15,
                __ATOMIC_RELAXED, __HIP_MEMORY_SCOPE_AGENT));

    float b1v[2], b2v[2], gbv[2];
    #pragma unroll
    for (int nt = 0; nt < 2; ++nt) {
        int u = n2 * 32 + nt * 16 + l15;
        b1v[nt] = fb1[u]; b2v[nt] = fb2[u]; gbv[nt] = gb[u];
    }

    unsigned short* hPb[2] = {hP0, hP1};
    int cur = 0;

    #pragma unroll 1
    for (int st = 0; st < NSTEP; ++st) {
        const unsigned short* hsrc = (st == 0) ? hE0 : hPb[cur];
        const int mtbase = (st == 0) ? wv : (g2 * 8 + wv);
        // ---- phase A: u = tanh(h W1^T + b1)  AND  g-pre = h gW^T (h-frags read once) ----
        f32x4 au[2] = {zz, zz}, ag[2] = {zz, zz};
        #pragma unroll 2
        for (int kt = 0; kt < 16; ++kt) {
            bf16x8 ah, al;
            ld_frag(hsrc + ((size_t)(mtbase * 16 + kt) * 64 + lane) * 16, ah, al);
            #pragma unroll
            for (int nt = 0; nt < 2; ++nt) {
                au[nt] = mfma3(ah, al, w1_p + ((size_t)((n2 * 2 + nt) * 16 + kt) * 64 + lane) * 16, au[nt]);
                ag[nt] = mfma3(ah, al, gw_p + ((size_t)((n2 * 2 + nt) * 16 + kt) * 64 + lane) * 16, ag[nt]);
            }
        }
        #pragma unroll
        for (int nt = 0; nt < 2; ++nt)
            #pragma unroll
            for (int v = 0; v < 4; ++v) {
                unsigned short hi, lo;
                split_bf(tanhf(au[nt][v] + b1v[nt]), hi, lo);
                Thi[wv * 16 + g4 * 4 + v][nt * 16 + l15] = hi;
                Tlo[wv * 16 + g4 * 4 + v][nt * 16 + l15] = lo;
            }
        __syncthreads();
        {
            int mt = tid >> 6, ln = tid & 63;
            bf16x8 vh = *(const bf16x8*)&Thi[mt * 16 + (ln & 15)][(ln >> 4) * 8];
            bf16x8 vl = *(const bf16x8*)&Tlo[mt * 16 + (ln & 15)][(ln >> 4) * 8];
            st_frag(uP + ((size_t)((g2 * 8 + mt) * 16 + n2) * 64 + ln) * 16, vh, vl);
        }
        gbar(ctr2, 16u * (2 * st + 1));
        // ---- phase B: f = u W2^T + b2 (u-frags only) ----
        f32x4 af[2] = {zz, zz};
        #pragma unroll 2
        for (int kt = 0; kt < 16; ++kt) {
            bf16x8 uh, ul;
            ld_frag(uP + ((size_t)((g2 * 8 + wv) * 16 + kt) * 64 + lane) * 16, uh, ul);
            #pragma unroll
            for (int nt = 0; nt < 2; ++nt)
                af[nt] = mfma3(uh, ul, w2_p + ((size_t)((n2 * 2 + nt) * 16 + kt) * 64 + lane) * 16, af[nt]);
        }
        #pragma unroll
        for (int nt = 0; nt < 2; ++nt)
            #pragma unroll
            for (int v = 0; v < 4; ++v) {
                int b = wv * 16 + g4 * 4 + v;
                float nz = noise[((size_t)(g2 * NSTEP + st) * NB + b) * HD + n2 * 32 + nt * 16 + l15];
                float f = af[nt][v] + b2v[nt];
                float gg = softp(ag[nt][v] + gbv[nt]);
                hreg[nt][v] += f * dt + gg * sqdt * nz;
                unsigned short hi, lo;
                split_bf(hreg[nt][v], hi, lo);
                Thi[b][nt * 16 + l15] = hi;
                Tlo[b][nt * 16 + l15] = lo;
            }
        __syncthreads();
        {
            int mt = tid >> 6, ln = tid & 63;
            bf16x8 vh = *(const bf16x8*)&Thi[mt * 16 + (ln & 15)][(ln >> 4) * 8];
            bf16x8 vl = *(const bf16x8*)&Tlo[mt * 16 + (ln & 15)][(ln >> 4) * 8];
            st_frag(hPb[cur ^ 1] + ((size_t)((g2 * 8 + mt) * 16 + n2) * 64 + ln) * 16, vh, vl);
        }
        cur ^= 1;
        gbar(ctr2, 16u * (2 * st + 2));
    }

    // =============== decoder GRU + out-proj ===============
    float crv[2], czv[2], binv[2], bhnv[2];
    #pragma unroll
    for (int nt = 0; nt < 2; ++nt) {
        int u = n2 * 32 + nt * 16 + l15;
        crv[nt] = dbih[u] + dbhh[u];
        czv[nt] = dbih[HD + u] + dbhh[HD + u];
        binv[nt] = dbih[2 * HD + u];
        bhnv[nt] = dbhh[2 * HD + u];
    }
    const float obias = (n2 < 2) ? outb[n2 * 16 + l15] : 0.f;

    #pragma unroll 1
    for (int j = 0; j <= NF; ++j) {
        const unsigned short* hsrc = hPb[cur];
        f32x4 ar[2] = {zz, zz}, az2[2] = {zz, zz}, anh[2] = {zz, zz}, ao = zz;
        if (j < NF || n2 < 2) {
            #pragma unroll 2
            for (int kt = 0; kt < 16; ++kt) {
                bf16x8 ah, al;
                ld_frag(hsrc + ((size_t)((g2 * 8 + wv) * 16 + kt) * 64 + lane) * 16, ah, al);
                if (j < NF) {
                    #pragma unroll
                    for (int nt = 0; nt < 2; ++nt) {
                        int nn = n2 * 2 + nt;
                        ar[nt]  = mfma3(ah, al, dwhh_p + ((size_t)((0 * 32 + nn) * 16 + kt) * 64 + lane) * 16, ar[nt]);
                        az2[nt] = mfma3(ah, al, dwhh_p + ((size_t)((1 * 32 + nn) * 16 + kt) * 64 + lane) * 16, az2[nt]);
                        anh[nt] = mfma3(ah, al, dwhh_p + ((size_t)((2 * 32 + nn) * 16 + kt) * 64 + lane) * 16, anh[nt]);
                    }
                }
                if (j >= 1 && n2 < 2)
                    ao = mfma3(ah, al, outw_p + ((size_t)(n2 * 16 + kt) * 64 + lane) * 16, ao);
            }
        }
        if (j >= 1 && n2 < 2) {
            #pragma unroll
            for (int v = 0; v < 4; ++v) {
                int b = wv * 16 + g4 * 4 + v;
                out[(((size_t)g2 * NB + b) * NI + (n2 * 16 + l15)) * NF + (j - 1)] = ao[v] + obias;
            }
        }
        if (j < NF) {
            #pragma unroll
            for (int nt = 0; nt < 2; ++nt)
                #pragma unroll
                for (int v = 0; v < 4; ++v) {
                    int b = wv * 16 + g4 * 4 + v;
                    float r = sigm(ar[nt][v] + crv[nt]);
                    float z = sigm(az2[nt][v] + czv[nt]);
                    float nn2 = tanhf(binv[nt] + r * (anh[nt][v] + bhnv[nt]));
                    hreg[nt][v] = (1.f - z) * nn2 + z * hreg[nt][v];
                    unsigned short hi, lo;
                    split_bf(hreg[nt][v], hi, lo);
                    Thi[b][nt * 16 + l15] = hi;
                    Tlo[b][nt * 16 + l15] = lo;
                }
            __syncthreads();
            {
                int mt = tid >> 6, ln = tid & 63;
                bf16x8 vh = *(const bf16x8*)&Thi[mt * 16 + (ln & 15)][(ln >> 4) * 8];
                bf16x8 vl = *(const bf16x8*)&Tlo[mt * 16 + (ln & 15)][(ln >> 4) * 8];
                st_frag(hPb[cur ^ 1] + ((size_t)((g2 * 8 + mt) * 16 + n2) * 64 + ln) * 16, vh, vl);
            }
            cur ^= 1;
        }
        gbar(ctr2, 16u * (2 * NSTEP + j + 1));
    }
}

extern "C" void kernel_launch(void* const* d_in, const int* in_sizes, int n_in,
                              void* d_out, int out_size, void* d_ws, size_t ws_size,
                              hipStream_t stream) {
    const float* x       = (const float*)d_in[0];
    const float* noise   = (const float*)d_in[1];
    const float* enc_Wih = (const float*)d_in[2];
    const float* enc_Whh = (const float*)d_in[3];
    const float* enc_bih = (const float*)d_in[4];
    const float* enc_bhh = (const float*)d_in[5];
    const float* f_W1    = (const float*)d_in[6];
    const float* f_b1    = (const float*)d_in[7];
    const float* f_W2    = (const float*)d_in[8];
    const float* f_b2    = (const float*)d_in[9];
    const float* g_W     = (const float*)d_in[10];
    const float* g_b     = (const float*)d_in[11];
    const float* dec_Whh = (const float*)d_in[13];
    const float* dec_bih = (const float*)d_in[14];
    const float* dec_bhh = (const float*)d_in[15];
    const float* out_W   = (const float*)d_in[16];
    const float* out_b   = (const float*)d_in[17];
    float* out = (float*)d_out;

    char* ws = (char*)d_ws;
    unsigned short* whh_p  = (unsigned short*)(ws + 0);          // 3 MB
    unsigned short* wih_p  = (unsigned short*)(ws + 3145728);    // 192 KB
    unsigned short* w1_p   = (unsigned short*)(ws + 3342336);    // 1 MB
    unsigned short* w2_p   = (unsigned short*)(ws + 4390912);    // 1 MB
    unsigned short* gw_p   = (unsigned short*)(ws + 5439488);    // 1 MB
    unsigned short* dwhh_p = (unsigned short*)(ws + 6488064);    // 3 MB
    unsigned short* outw_p = (unsigned short*)(ws + 9633792);    // 64 KB
    unsigned short* xhi    = (unsigned short*)(ws + 9699328);    // 768 KB
    unsigned short* xlo    = (unsigned short*)(ws + 10485760);   // 768 KB
    unsigned short* hE1    = (unsigned short*)(ws + 11272192);   // 256 KB
    unsigned short* hP0    = (unsigned short*)(ws + 11534336);   // 4 MB
    unsigned short* hP1    = (unsigned short*)(ws + 15728640);   // 4 MB
    unsigned short* uP     = (unsigned short*)(ws + 19922944);   // 4 MB
    unsigned*       h_encF = (unsigned*)(ws + 24117248);         // 256 KB
    unsigned*       bar    = (unsigned*)(ws + 24379392);         // 2 KB
    unsigned short* hE0    = (unsigned short*)(ws + 24381440);   // 256 KB (contiguous w/ bar for one memset)

    // zero barrier counters + initial encoder h fragments
    hipMemsetAsync(ws + 24379392, 0, 2048 + 262144, stream);

    pack_w<<<384, 256, 0, stream>>>(enc_Whh, whh_p, 3 * HD, HD);
    pack_w<<<24, 256, 0, stream>>>(enc_Wih, wih_p, 3 * HD, NI);
    pack_w<<<128, 256, 0, stream>>>(f_W1, w1_p, HD, HD);
    pack_w<<<128, 256, 0, stream>>>(f_W2, w2_p, HD, HD);
    pack_w<<<128, 256, 0, stream>>>(g_W, gw_p, HD, HD);
    pack_w<<<384, 256, 0, stream>>>(dec_Whh, dwhh_p, 3 * HD, HD);
    pack_w<<<8, 256, 0, stream>>>(out_W, outw_p, NI, HD);
    pack_x<<<48, 256, 0, stream>>>(x, xhi, xlo);

    void* args[] = {
        (void*)&xhi, (void*)&xlo, (void*)&wih_p, (void*)&whh_p,
        (void*)&w1_p, (void*)&w2_p, (void*)&gw_p, (void*)&dwhh_p, (void*)&outw_p,
        (void*)&enc_bih, (void*)&enc_bhh, (void*)&f_b1, (void*)&f_b2,
        (void*)&g_b, (void*)&dec_bih, (void*)&dec_bhh, (void*)&out_b,
        (void*)&noise,
        (void*)&hE0, (void*)&hE1, (void*)&hP0, (void*)&hP1, (void*)&uP,
        (void*)&h_encF, (void*)&out, (void*)&bar
    };
    hipLaunchCooperativeKernel((void*)coop_all, dim3(256), dim3(512), args, 0, stream);
}

// Round 6
// 2170.220 us; speedup vs baseline: 8.0271x; 1.1773x over previous
//
#include <hip/hip_runtime.h>
#include <math.h>

typedef __bf16 bf16x8 __attribute__((ext_vector_type(8)));
typedef float f32x4 __attribute__((ext_vector_type(4)));
typedef unsigned long long u64;

#define HD 512
#define NB 128
#define NI 32
#define NL 96
#define NS 16
#define NF 24
#define NSTEP 23
#define TS 40   // padded LDS transpose stride (shorts)

#define MFMA16(a,b,c) __builtin_amdgcn_mfma_f32_16x16x32_bf16(a,b,c,0,0,0)

__device__ __forceinline__ unsigned short f2bf(float f) {
    union { float f; unsigned u; } v; v.f = f;
    unsigned r = v.u + 0x7fffu + ((v.u >> 16) & 1u);
    return (unsigned short)(r >> 16);
}
__device__ __forceinline__ float bf2f(unsigned short h) {
    union { unsigned u; float f; } v; v.u = ((unsigned)h) << 16;
    return v.f;
}
__device__ __forceinline__ void split_bf(float v, unsigned short& hi, unsigned short& lo) {
    unsigned short h = f2bf(v);
    hi = h;
    lo = f2bf(v - bf2f(h));
}
__device__ __forceinline__ float sigm(float x) { return 1.0f / (1.0f + __expf(-x)); }
__device__ __forceinline__ float softp(float x) {
    return fmaxf(x, 0.0f) + log1pf(__expf(-fabsf(x)));
}
__device__ __forceinline__ bf16x8 ld8(const unsigned short* p) {
    return *reinterpret_cast<const bf16x8*>(p);
}
__device__ __forceinline__ f32x4 mfma3(bf16x8 ahi, bf16x8 alo, const unsigned short* bp, f32x4 c) {
    bf16x8 bhi = ld8(bp);
    bf16x8 blo = ld8(bp + 8);
    c = MFMA16(ahi, bhi, c);
    c = MFMA16(alo, bhi, c);
    c = MFMA16(ahi, blo, c);
    return c;
}

// ---- device-coherent state exchange: relaxed agent-scope 8B atomics ----
// SoA tile layout: a 64-lane fragment tile is 4 planes of [64] u64
// (tile[j*64 + lane]); each store/load instruction covers a contiguous
// 512 B run across the wave -> no partial-granule write amplification.
__device__ __forceinline__ void st_frag(u64* tile, int lane, bf16x8 hi, bf16x8 lo) {
    union { bf16x8 v; u64 q[2]; } h, l;
    h.v = hi; l.v = lo;
    __hip_atomic_store(tile + 0 * 64 + lane, h.q[0], __ATOMIC_RELAXED, __HIP_MEMORY_SCOPE_AGENT);
    __hip_atomic_store(tile + 1 * 64 + lane, h.q[1], __ATOMIC_RELAXED, __HIP_MEMORY_SCOPE_AGENT);
    __hip_atomic_store(tile + 2 * 64 + lane, l.q[0], __ATOMIC_RELAXED, __HIP_MEMORY_SCOPE_AGENT);
    __hip_atomic_store(tile + 3 * 64 + lane, l.q[1], __ATOMIC_RELAXED, __HIP_MEMORY_SCOPE_AGENT);
}
__device__ __forceinline__ void ld_frag(const u64* tile, int lane, bf16x8& hi, bf16x8& lo) {
    union { bf16x8 v; u64 q[2]; } h, l;
    h.q[0] = __hip_atomic_load(tile + 0 * 64 + lane, __ATOMIC_RELAXED, __HIP_MEMORY_SCOPE_AGENT);
    h.q[1] = __hip_atomic_load(tile + 1 * 64 + lane, __ATOMIC_RELAXED, __HIP_MEMORY_SCOPE_AGENT);
    l.q[0] = __hip_atomic_load(tile + 2 * 64 + lane, __ATOMIC_RELAXED, __HIP_MEMORY_SCOPE_AGENT);
    l.q[1] = __hip_atomic_load(tile + 3 * 64 + lane, __ATOMIC_RELAXED, __HIP_MEMORY_SCOPE_AGENT);
    hi = h.v; lo = l.v;
}
// barrier: drain own vmem, block-barrier, relaxed counter, spin. No __threadfence
// -> no L2 writeback/invalidate -> weights stay L2-resident.
__device__ __forceinline__ void gbar(unsigned* ctr, unsigned target) {
    __builtin_amdgcn_s_waitcnt(0);
    __syncthreads();
    if (threadIdx.x == 0) {
        __hip_atomic_fetch_add(ctr, 1u, __ATOMIC_RELAXED, __HIP_MEMORY_SCOPE_AGENT);
        while (__hip_atomic_load(ctr, __ATOMIC_RELAXED, __HIP_MEMORY_SCOPE_AGENT) < target)
            __builtin_amdgcn_s_sleep(2);
    }
    __syncthreads();
}

// ---------- prep: pack W[N][K] fp32 -> split bf16 B-fragments ----------
__global__ void pack_w(const float* __restrict__ W, unsigned short* __restrict__ Wp,
                       int N, int K) {
    int idx = blockIdx.x * 256 + threadIdx.x;
    int total = (N / 16) * (K / 32) * 64;
    if (idx >= total) return;
    int lane = idx & 63;
    int t2 = idx >> 6;
    int KT = K / 32;
    int kt = t2 % KT, nt = t2 / KT;
    const float* src = W + (size_t)(nt * 16 + (lane & 15)) * K + kt * 32 + (lane >> 4) * 8;
    unsigned short* dst = Wp + (size_t)idx * 16;
    #pragma unroll
    for (int j = 0; j < 8; ++j) split_bf(src[j], dst[j], dst[8 + j]);
}

// ---------- prep: x[B][I][L] fp32 -> xhi/xlo [L][B][I] bf16 ----------
__global__ void pack_x(const float* __restrict__ x, unsigned short* __restrict__ xhi,
                       unsigned short* __restrict__ xlo) {
    int idx = blockIdx.x * 256 + threadIdx.x;
    if (idx >= NL * NB) return;
    int b = idx % NB, l = idx / NB;
    size_t base = (size_t)(l * NB + b) * NI;
    #pragma unroll
    for (int i = 0; i < NI; ++i)
        split_bf(x[((size_t)b * NI + i) * NL + l], xhi[base + i], xlo[base + i]);
}

// =================== fused cooperative kernel ===================
__global__ __launch_bounds__(512) void coop_all(
    const unsigned short* __restrict__ xhi, const unsigned short* __restrict__ xlo,
    const unsigned short* __restrict__ wih_p, const unsigned short* __restrict__ whh_p,
    const unsigned short* __restrict__ w1_p, const unsigned short* __restrict__ w2_p,
    const unsigned short* __restrict__ gw_p, const unsigned short* __restrict__ dwhh_p,
    const unsigned short* __restrict__ outw_p,
    const float* __restrict__ ebih, const float* __restrict__ ebhh,
    const float* __restrict__ fb1, const float* __restrict__ fb2,
    const float* __restrict__ gb, const float* __restrict__ dbih,
    const float* __restrict__ dbhh, const float* __restrict__ outb,
    const float* __restrict__ noise,
    u64* hE0, u64* hE1, u64* hP0, u64* hP1, u64* uP,
    unsigned* h_encF, float* out, unsigned* bar)
{
    const int bid = blockIdx.x;
    const int tid = threadIdx.x, lane = tid & 63, wv = tid >> 6;
    const int l15 = lane & 15, g4 = lane >> 4;
    const f32x4 zz = {0.f, 0.f, 0.f, 0.f};

    __shared__ float pred[4][8][16][16];
    __shared__ __align__(16) unsigned short Thi[128][TS];
    __shared__ __align__(16) unsigned short Tlo[128][TS];

    // =============== encoder: group g = m-tile (16 rows), slice n = 16 units ===============
    {
        const int g = bid & 7, n = bid >> 3;
        unsigned* ctr = bar + (1 + g) * 16;
        float hcell = 0.f;
        float cr = 0.f, cz = 0.f, binx = 0.f, bhnn = 0.f;
        const int crow = tid >> 4, cunit = tid & 15;
        if (tid < 256) {
            int u = n * 16 + cunit;
            cr = ebih[u] + ebhh[u];
            cz = ebih[HD + u] + ebhh[HD + u];
            binx = ebih[2 * HD + u];
            bhnn = ebhh[2 * HD + u];
        }
        u64* hEbuf[2] = {hE0, hE1};
        #pragma unroll 1
        for (int l = 0; l < NL; ++l) {
            const u64* cur = hEbuf[l & 1];
            u64* nxt = hEbuf[(l & 1) ^ 1];
            f32x4 pr = zz, pz = zz, pnh = zz, pnx = zz;
            if (wv == 0) {
                size_t xb = (size_t)(l * NB + g * 16 + l15) * NI + g4 * 8;
                bf16x8 axh = ld8(xhi + xb), axl = ld8(xlo + xb);
                pr  = mfma3(axh, axl, wih_p + ((size_t)(0 * 32 + n) * 64 + lane) * 16, pr);
                pz  = mfma3(axh, axl, wih_p + ((size_t)(1 * 32 + n) * 64 + lane) * 16, pz);
                pnx = mfma3(axh, axl, wih_p + ((size_t)(2 * 32 + n) * 64 + lane) * 16, pnx);
            }
            #pragma unroll
            for (int kk = 0; kk < 2; ++kk) {
                int kt = wv * 2 + kk;
                bf16x8 ah, al;
                ld_frag(cur + (size_t)(g * 16 + kt) * 256, lane, ah, al);
                pr  = mfma3(ah, al, whh_p + ((size_t)((0 * 32 + n) * 16 + kt) * 64 + lane) * 16, pr);
                pz  = mfma3(ah, al, whh_p + ((size_t)((1 * 32 + n) * 16 + kt) * 64 + lane) * 16, pz);
                pnh = mfma3(ah, al, whh_p + ((size_t)((2 * 32 + n) * 16 + kt) * 64 + lane) * 16, pnh);
            }
            #pragma unroll
            for (int v = 0; v < 4; ++v) {
                pred[0][wv][g4 * 4 + v][l15] = pr[v];
                pred[1][wv][g4 * 4 + v][l15] = pz[v];
                pred[2][wv][g4 * 4 + v][l15] = pnh[v];
                if (wv == 0) pred[3][0][g4 * 4 + v][l15] = pnx[v];
            }
            __syncthreads();
            if (tid < 256) {
                float ar = 0.f, az = 0.f, anh_ = 0.f;
                #pragma unroll
                for (int w = 0; w < 8; ++w) {
                    ar += pred[0][w][crow][cunit];
                    az += pred[1][w][crow][cunit];
                    anh_ += pred[2][w][crow][cunit];
                }
                float anx_ = pred[3][0][crow][cunit];
                float r = sigm(ar + cr);
                float z = sigm(az + cz);
                float nn = tanhf(anx_ + binx + r * (anh_ + bhnn));
                hcell = (1.f - z) * nn + z * hcell;
                unsigned short hi, lo;
                split_bf(hcell, hi, lo);
                Thi[crow][cunit] = hi;
                Tlo[crow][cunit] = lo;
                if (l == NL - 1)
                    __hip_atomic_store(h_encF + (size_t)(g * 16 + crow) * HD + n * 16 + cunit,
                                       __float_as_uint(hcell),
                                       __ATOMIC_RELAXED, __HIP_MEMORY_SCOPE_AGENT);
            }
            __syncthreads();
            if (tid < 32) {
                int half = n & 1, kt = n >> 1;
                int lp = half * 32 + tid;
                bf16x8 vh = *(const bf16x8*)&Thi[tid & 15][(tid >> 4) * 8];
                bf16x8 vl = *(const bf16x8*)&Tlo[tid & 15][(tid >> 4) * 8];
                st_frag(nxt + (size_t)(g * 16 + kt) * 256, lp, vh, vl);
            }
            gbar(ctr, 32u * (l + 1));
        }
    }

    // full-grid barrier: h_encF + final frags (hE0) visible
    gbar(bar, 256u);

    // =============== SDE + decoder: group g2 = sample (128 rows), slice n2 = 32 units ===============
    const int g2 = (bid & 7) * 2 + ((bid >> 3) & 1);
    const int n2 = bid >> 4;
    unsigned* ctr2 = bar + (9 + g2) * 16;
    const float dt = (float)NF / (float)NSTEP;
    const float sqdt = sqrtf(dt);

    float hreg[2][4];
    #pragma unroll
    for (int nt = 0; nt < 2; ++nt)
        #pragma unroll
        for (int v = 0; v < 4; ++v)
            hreg[nt][v] = __uint_as_float(__hip_atomic_load(
                h_encF + (size_t)(wv * 16 + g4 * 4 + v) * HD + n2 * 32 + nt * 16 + l15,
                __ATOMIC_RELAXED, __HIP_MEMORY_SCOPE_AGENT));

    float b1v[2], b2v[2], gbv[2];
    #pragma unroll
    for (int nt = 0; nt < 2; ++nt) {
        int u = n2 * 32 + nt * 16 + l15;
        b1v[nt] = fb1[u]; b2v[nt] = fb2[u]; gbv[nt] = gb[u];
    }

    u64* hPb[2] = {hP0, hP1};
    int cur = 0;

    #pragma unroll 1
    for (int st = 0; st < NSTEP; ++st) {
        const u64* hsrc = (st == 0) ? hE0 : hPb[cur];
        const int mtbase = (st == 0) ? wv : (g2 * 8 + wv);
        // ---- phase A: u = tanh(h W1^T + b1)  AND  g-pre = h gW^T ----
        f32x4 au[2] = {zz, zz}, ag[2] = {zz, zz};
        #pragma unroll 2
        for (int kt = 0; kt < 16; ++kt) {
            bf16x8 ah, al;
            ld_frag(hsrc + (size_t)(mtbase * 16 + kt) * 256, lane, ah, al);
            #pragma unroll
            for (int nt = 0; nt < 2; ++nt) {
                au[nt] = mfma3(ah, al, w1_p + ((size_t)((n2 * 2 + nt) * 16 + kt) * 64 + lane) * 16, au[nt]);
                ag[nt] = mfma3(ah, al, gw_p + ((size_t)((n2 * 2 + nt) * 16 + kt) * 64 + lane) * 16, ag[nt]);
            }
        }
        #pragma unroll
        for (int nt = 0; nt < 2; ++nt)
            #pragma unroll
            for (int v = 0; v < 4; ++v) {
                unsigned short hi, lo;
                split_bf(tanhf(au[nt][v] + b1v[nt]), hi, lo);
                Thi[wv * 16 + g4 * 4 + v][nt * 16 + l15] = hi;
                Tlo[wv * 16 + g4 * 4 + v][nt * 16 + l15] = lo;
            }
        __syncthreads();
        {
            int mt = tid >> 6, ln = tid & 63;
            bf16x8 vh = *(const bf16x8*)&Thi[mt * 16 + (ln & 15)][(ln >> 4) * 8];
            bf16x8 vl = *(const bf16x8*)&Tlo[mt * 16 + (ln & 15)][(ln >> 4) * 8];
            st_frag(uP + (size_t)((g2 * 8 + mt) * 16 + n2) * 256, ln, vh, vl);
        }
        gbar(ctr2, 16u * (2 * st + 1));
        // ---- phase B: f = u W2^T + b2 ----
        f32x4 af[2] = {zz, zz};
        #pragma unroll 2
        for (int kt = 0; kt < 16; ++kt) {
            bf16x8 uh, ul;
            ld_frag(uP + (size_t)((g2 * 8 + wv) * 16 + kt) * 256, lane, uh, ul);
            #pragma unroll
            for (int nt = 0; nt < 2; ++nt)
                af[nt] = mfma3(uh, ul, w2_p + ((size_t)((n2 * 2 + nt) * 16 + kt) * 64 + lane) * 16, af[nt]);
        }
        #pragma unroll
        for (int nt = 0; nt < 2; ++nt)
            #pragma unroll
            for (int v = 0; v < 4; ++v) {
                int b = wv * 16 + g4 * 4 + v;
                float nz = noise[((size_t)(g2 * NSTEP + st) * NB + b) * HD + n2 * 32 + nt * 16 + l15];
                float f = af[nt][v] + b2v[nt];
                float gg = softp(ag[nt][v] + gbv[nt]);
                hreg[nt][v] += f * dt + gg * sqdt * nz;
                unsigned short hi, lo;
                split_bf(hreg[nt][v], hi, lo);
                Thi[b][nt * 16 + l15] = hi;
                Tlo[b][nt * 16 + l15] = lo;
            }
        __syncthreads();
        {
            int mt = tid >> 6, ln = tid & 63;
            bf16x8 vh = *(const bf16x8*)&Thi[mt * 16 + (ln & 15)][(ln >> 4) * 8];
            bf16x8 vl = *(const bf16x8*)&Tlo[mt * 16 + (ln & 15)][(ln >> 4) * 8];
            st_frag(hPb[cur ^ 1] + (size_t)((g2 * 8 + mt) * 16 + n2) * 256, ln, vh, vl);
        }
        cur ^= 1;
        gbar(ctr2, 16u * (2 * st + 2));
    }

    // =============== decoder GRU + out-proj ===============
    float crv[2], czv[2], binv[2], bhnv[2];
    #pragma unroll
    for (int nt = 0; nt < 2; ++nt) {
        int u = n2 * 32 + nt * 16 + l15;
        crv[nt] = dbih[u] + dbhh[u];
        czv[nt] = dbih[HD + u] + dbhh[HD + u];
        binv[nt] = dbih[2 * HD + u];
        bhnv[nt] = dbhh[2 * HD + u];
    }
    const float obias = (n2 < 2) ? outb[n2 * 16 + l15] : 0.f;

    #pragma unroll 1
    for (int j = 0; j <= NF; ++j) {
        const u64* hsrc = hPb[cur];
        f32x4 ar[2] = {zz, zz}, az2[2] = {zz, zz}, anh[2] = {zz, zz}, ao = zz;
        if (j < NF || n2 < 2) {
            #pragma unroll 2
            for (int kt = 0; kt < 16; ++kt) {
                bf16x8 ah, al;
                ld_frag(hsrc + (size_t)((g2 * 8 + wv) * 16 + kt) * 256, lane, ah, al);
                if (j < NF) {
                    #pragma unroll
                    for (int nt = 0; nt < 2; ++nt) {
                        int nn = n2 * 2 + nt;
                        ar[nt]  = mfma3(ah, al, dwhh_p + ((size_t)((0 * 32 + nn) * 16 + kt) * 64 + lane) * 16, ar[nt]);
                        az2[nt] = mfma3(ah, al, dwhh_p + ((size_t)((1 * 32 + nn) * 16 + kt) * 64 + lane) * 16, az2[nt]);
                        anh[nt] = mfma3(ah, al, dwhh_p + ((size_t)((2 * 32 + nn) * 16 + kt) * 64 + lane) * 16, anh[nt]);
                    }
                }
                if (j >= 1 && n2 < 2)
                    ao = mfma3(ah, al, outw_p + ((size_t)(n2 * 16 + kt) * 64 + lane) * 16, ao);
            }
        }
        if (j >= 1 && n2 < 2) {
            #pragma unroll
            for (int v = 0; v < 4; ++v) {
                int b = wv * 16 + g4 * 4 + v;
                out[(((size_t)g2 * NB + b) * NI + (n2 * 16 + l15)) * NF + (j - 1)] = ao[v] + obias;
            }
        }
        if (j < NF) {
            #pragma unroll
            for (int nt = 0; nt < 2; ++nt)
                #pragma unroll
                for (int v = 0; v < 4; ++v) {
                    int b = wv * 16 + g4 * 4 + v;
                    float r = sigm(ar[nt][v] + crv[nt]);
                    float z = sigm(az2[nt][v] + czv[nt]);
                    float nn2 = tanhf(binv[nt] + r * (anh[nt][v] + bhnv[nt]));
                    hreg[nt][v] = (1.f - z) * nn2 + z * hreg[nt][v];
                    unsigned short hi, lo;
                    split_bf(hreg[nt][v], hi, lo);
                    Thi[b][nt * 16 + l15] = hi;
                    Tlo[b][nt * 16 + l15] = lo;
                }
            __syncthreads();
            {
                int mt = tid >> 6, ln = tid & 63;
                bf16x8 vh = *(const bf16x8*)&Thi[mt * 16 + (ln & 15)][(ln >> 4) * 8];
                bf16x8 vl = *(const bf16x8*)&Tlo[mt * 16 + (ln & 15)][(ln >> 4) * 8];
                st_frag(hPb[cur ^ 1] + (size_t)((g2 * 8 + mt) * 16 + n2) * 256, ln, vh, vl);
            }
            cur ^= 1;
        }
        gbar(ctr2, 16u * (2 * NSTEP + j + 1));
    }
}

extern "C" void kernel_launch(void* const* d_in, const int* in_sizes, int n_in,
                              void* d_out, int out_size, void* d_ws, size_t ws_size,
                              hipStream_t stream) {
    const float* x       = (const float*)d_in[0];
    const float* noise   = (const float*)d_in[1];
    const float* enc_Wih = (const float*)d_in[2];
    const float* enc_Whh = (const float*)d_in[3];
    const float* enc_bih = (const float*)d_in[4];
    const float* enc_bhh = (const float*)d_in[5];
    const float* f_W1    = (const float*)d_in[6];
    const float* f_b1    = (const float*)d_in[7];
    const float* f_W2    = (const float*)d_in[8];
    const float* f_b2    = (const float*)d_in[9];
    const float* g_W     = (const float*)d_in[10];
    const float* g_b     = (const float*)d_in[11];
    const float* dec_Whh = (const float*)d_in[13];
    const float* dec_bih = (const float*)d_in[14];
    const float* dec_bhh = (const float*)d_in[15];
    const float* out_W   = (const float*)d_in[16];
    const float* out_b   = (const float*)d_in[17];
    float* out = (float*)d_out;

    char* ws = (char*)d_ws;
    unsigned short* whh_p  = (unsigned short*)(ws + 0);          // 3 MB
    unsigned short* wih_p  = (unsigned short*)(ws + 3145728);    // 192 KB
    unsigned short* w1_p   = (unsigned short*)(ws + 3342336);    // 1 MB
    unsigned short* w2_p   = (unsigned short*)(ws + 4390912);    // 1 MB
    unsigned short* gw_p   = (unsigned short*)(ws + 5439488);    // 1 MB
    unsigned short* dwhh_p = (unsigned short*)(ws + 6488064);    // 3 MB
    unsigned short* outw_p = (unsigned short*)(ws + 9633792);    // 64 KB
    unsigned short* xhi    = (unsigned short*)(ws + 9699328);    // 768 KB
    unsigned short* xlo    = (unsigned short*)(ws + 10485760);   // 768 KB
    u64*            hE1    = (u64*)(ws + 11272192);              // 256 KB
    u64*            hP0    = (u64*)(ws + 11534336);              // 4 MB
    u64*            hP1    = (u64*)(ws + 15728640);              // 4 MB
    u64*            uP     = (u64*)(ws + 19922944);              // 4 MB
    unsigned*       h_encF = (unsigned*)(ws + 24117248);         // 256 KB
    unsigned*       bar    = (unsigned*)(ws + 24379392);         // 2 KB
    u64*            hE0    = (u64*)(ws + 24381440);              // 256 KB (contiguous w/ bar)

    // zero barrier counters + initial encoder h fragments
    hipMemsetAsync(ws + 24379392, 0, 2048 + 262144, stream);

    pack_w<<<384, 256, 0, stream>>>(enc_Whh, whh_p, 3 * HD, HD);
    pack_w<<<24, 256, 0, stream>>>(enc_Wih, wih_p, 3 * HD, NI);
    pack_w<<<128, 256, 0, stream>>>(f_W1, w1_p, HD, HD);
    pack_w<<<128, 256, 0, stream>>>(f_W2, w2_p, HD, HD);
    pack_w<<<128, 256, 0, stream>>>(g_W, gw_p, HD, HD);
    pack_w<<<384, 256, 0, stream>>>(dec_Whh, dwhh_p, 3 * HD, HD);
    pack_w<<<8, 256, 0, stream>>>(out_W, outw_p, NI, HD);
    pack_x<<<48, 256, 0, stream>>>(x, xhi, xlo);

    void* args[] = {
        (void*)&xhi, (void*)&xlo, (void*)&wih_p, (void*)&whh_p,
        (void*)&w1_p, (void*)&w2_p, (void*)&gw_p, (void*)&dwhh_p, (void*)&outw_p,
        (void*)&enc_bih, (void*)&enc_bhh, (void*)&f_b1, (void*)&f_b2,
        (void*)&g_b, (void*)&dec_bih, (void*)&dec_bhh, (void*)&out_b,
        (void*)&noise,
        (void*)&hE0, (void*)&hE1, (void*)&hP0, (void*)&hP1, (void*)&uP,
        (void*)&h_encF, (void*)&out, (void*)&bar
    };
    hipLaunchCooperativeKernel((void*)coop_all, dim3(256), dim3(512), args, 0, stream);
}